// Round 1
// baseline (958.583 us; speedup 1.0000x reference)
//
#include <hip/hip_runtime.h>

typedef unsigned short u16;
typedef __attribute__((ext_vector_type(4))) int i4;
typedef __attribute__((ext_vector_type(4))) unsigned u4;
typedef __attribute__((ext_vector_type(4))) unsigned short us4;
typedef __attribute__((ext_vector_type(8))) short short8;
typedef __attribute__((ext_vector_type(4))) float f4;

#define D_MODEL 1024
#define ROWS 4096      // B*L and MEM_SIZE
#define NHEAD 8
#define DH 128
#define TOPK 409
#define NUPD 1636      // B*TOPK
#define NBATCH 4

__device__ __forceinline__ u16 f2bf(float f) {
  unsigned u = __builtin_bit_cast(unsigned, f);
  u += 0x7fffu + ((u >> 16) & 1u);
  return (u16)(u >> 16);
}
__device__ __forceinline__ float gelu_f(float v) {
  return 0.5f * v * (1.0f + erff(v * 0.70710678118654752f));
}
__device__ __forceinline__ void gload16(const void* g, void* l) {
  __builtin_amdgcn_global_load_lds((const __attribute__((address_space(1))) void*)g,
                                   (__attribute__((address_space(3))) void*)l, 16, 0, 0);
}

// ---------------- convert f32 -> bf16 (vectorized) ----------------
__global__ __launch_bounds__(256) void conv_kernel(const float* __restrict__ in,
                                                   u16* __restrict__ out, int n4) {
  int i = blockIdx.x * 256 + threadIdx.x;
  if (i < n4) {
    f4 v = ((const f4*)in)[i];
    us4 o;
    o.x = f2bf(v.x); o.y = f2bf(v.y); o.z = f2bf(v.z); o.w = f2bf(v.w);
    ((us4*)out)[i] = o;
  }
}

// ---------------- weight transpose: w[K][N] f32 -> wt[N][K] bf16 ----------------
__global__ __launch_bounds__(256) void wtrans_kernel(const float* __restrict__ w,
                                                     u16* __restrict__ wt, int K, int N) {
  __shared__ float t[32][33];
  int tx = threadIdx.x & 31, ty = threadIdx.x >> 5;
  int k0 = blockIdx.y * 32, n0 = blockIdx.x * 32;
  for (int r = 0; r < 4; ++r)
    t[ty + r * 8][tx] = w[(size_t)(k0 + ty + r * 8) * N + n0 + tx];
  __syncthreads();
  for (int r = 0; r < 4; ++r)
    wt[(size_t)(n0 + ty + r * 8) * K + k0 + tx] = f2bf(t[tx][ty + r * 8]);
}

// ---------------- bf16 GEMM: C[M][N] = A[M][K] * BT[N][K]^T + bias ----------------
// EPI: 0 = bf16 store, 1 = GELU + bf16 store, 2 = f32 store, 3 = bf16 transposed store (C^T [N][M])
template <int EPI>
__global__ __launch_bounds__(256) void gemm_bt(const u16* __restrict__ A,
                                               const u16* __restrict__ BT,
                                               const float* __restrict__ bias,
                                               void* __restrict__ C, int M, int N, int K) {
  __shared__ __align__(16) u16 al[128 * 32];
  __shared__ __align__(16) u16 bl[128 * 32];
  const int tid = threadIdx.x;
  const int lane = tid & 63, wid = tid >> 6;
  const int g = lane >> 4, qi = lane & 15;
  const int m0 = blockIdx.y * 128, n0 = blockIdx.x * 128;
  const int wr = wid >> 1, wc = wid & 1;
  f4 acc[4][4] = {};
  const int nk = K >> 5;
  const int c0 = tid, c1 = tid + 256;
  const int ar0 = c0 >> 2, ab0 = (c0 & 3) * 8;
  const int ar1 = c1 >> 2, ab1 = (c1 & 3) * 8;
  for (int kt = 0; kt < nk; ++kt) {
    const int k0 = kt * 32;
    gload16(A + (size_t)(m0 + ar0) * K + k0 + ab0, (char*)al + c0 * 16);
    gload16(A + (size_t)(m0 + ar1) * K + k0 + ab1, (char*)al + c1 * 16);
    gload16(BT + (size_t)(n0 + ar0) * K + k0 + ab0, (char*)bl + c0 * 16);
    gload16(BT + (size_t)(n0 + ar1) * K + k0 + ab1, (char*)bl + c1 * 16);
    __syncthreads();
    short8 af[4], bfr[4];
    for (int i = 0; i < 4; ++i)
      af[i] = *(const short8*)((const char*)al + (wr * 64 + i * 16 + qi) * 64 + g * 16);
    for (int sn = 0; sn < 4; ++sn)
      bfr[sn] = *(const short8*)((const char*)bl + (wc * 64 + sn * 16 + qi) * 64 + g * 16);
    for (int i = 0; i < 4; ++i)
      for (int sn = 0; sn < 4; ++sn)
        acc[i][sn] = __builtin_amdgcn_mfma_f32_16x16x32_bf16(af[i], bfr[sn], acc[i][sn], 0, 0, 0);
    __syncthreads();
  }
  if constexpr (EPI == 3) {
    // transposed store via padded LDS (conflict-free column read), coalesced global write
    __shared__ u16 t[4][64][66];
    for (int i = 0; i < 4; ++i)
      for (int sn = 0; sn < 4; ++sn) {
        float bv = bias[n0 + wc * 64 + sn * 16 + qi];
        for (int jj = 0; jj < 4; ++jj)
          t[wid][i * 16 + g * 4 + jj][sn * 16 + qi] = f2bf(acc[i][sn][jj] + bv);
      }
    __syncthreads();
    for (int nl = 0; nl < 64; ++nl) {
      u16 v = t[wid][lane][nl];
      ((u16*)C)[(size_t)(n0 + wc * 64 + nl) * M + m0 + wr * 64 + lane] = v;
    }
  } else {
    for (int i = 0; i < 4; ++i) {
      int row = m0 + wr * 64 + i * 16 + g * 4;
      for (int sn = 0; sn < 4; ++sn) {
        int col = n0 + wc * 64 + sn * 16 + qi;
        float bv = bias[col];
        for (int jj = 0; jj < 4; ++jj) {
          float v = acc[i][sn][jj] + bv;
          if constexpr (EPI == 1) v = gelu_f(v);
          if constexpr (EPI == 2)
            ((float*)C)[(size_t)(row + jj) * N + col] = v;
          else
            ((u16*)C)[(size_t)(row + jj) * N + col] = f2bf(v);
        }
      }
    }
  }
}

// ---------------- flash cross-attention ----------------
// q[4096][1024] bf16, k[4096][1024] bf16, vT[1024][4096] bf16 -> ctx[4096][1024] bf16
// grid (L/64, H, B), 256 threads (4 waves, 16 q-rows each). Swapped QK^T: lane-local softmax rows.
__global__ __launch_bounds__(256) void attn_kernel(const u16* __restrict__ q,
                                                   const u16* __restrict__ kp,
                                                   const u16* __restrict__ vT,
                                                   u16* __restrict__ ctx) {
  __shared__ __align__(16) char kl[64 * 256];   // K tile [64][128] bf16, 16B-block XOR swizzle
  __shared__ __align__(16) char vl[128 * 128];  // V^T tile [128][64] bf16, swizzled
  const int tid = threadIdx.x;
  const int lane = tid & 63, wid = tid >> 6;
  const int g = lane >> 4, qi = lane & 15;
  const int h = blockIdx.y, b = blockIdx.z;
  const int qrow = b * 1024 + blockIdx.x * 64 + wid * 16 + qi;
  const float scale = 0.08838834764831845f;  // 1/sqrt(128)

  short8 qf[4];
  for (int kk = 0; kk < 4; ++kk)
    qf[kk] = *(const short8*)(q + (size_t)qrow * 1024 + h * 128 + kk * 32 + g * 8);

  f4 ct[8] = {};
  float mrun = -1e30f, lsum = 0.0f;

  for (int mt = 0; mt < 64; ++mt) {
    const int m0 = mt * 64;
    __syncthreads();
    for (int i = 0; i < 4; ++i) {  // stage K: 64 rows x 16 16B-blocks
      int c = tid + i * 256, r = c >> 4, blk = c & 15;
      *(i4*)(kl + r * 256 + (blk ^ (r & 7)) * 16) =
          *(const i4*)(kp + (size_t)(m0 + r) * 1024 + h * 128 + blk * 8);
    }
    for (int i = 0; i < 4; ++i) {  // stage V^T: 128 rows x 8 16B-blocks
      int c = tid + i * 256, r = c >> 3, blk = c & 7;
      *(i4*)(vl + r * 128 + (blk ^ (r & 7)) * 16) =
          *(const i4*)(vT + (size_t)(h * 128 + r) * 4096 + m0 + blk * 8);
    }
    __syncthreads();

    // S^T = K_tile x Q^T : lane holds S^T[n = 16s + 4g + jj][q = qi]
    f4 st[4] = {};
    for (int s = 0; s < 4; ++s) {
      int n = s * 16 + qi;
      const char* krow = kl + n * 256;
      int sw = n & 7;
      for (int kk = 0; kk < 4; ++kk) {
        short8 a = *(const short8*)(krow + ((kk * 4 + g) ^ sw) * 16);
        st[s] = __builtin_amdgcn_mfma_f32_16x16x32_bf16(a, qf[kk], st[s], 0, 0, 0);
      }
    }
    // online softmax (row = qi, replicated across the 4 lane-groups)
    float sv[16];
    float tmax = -1e30f;
    for (int s = 0; s < 4; ++s)
      for (int jj = 0; jj < 4; ++jj) {
        float v = st[s][jj] * scale;
        sv[s * 4 + jj] = v;
        tmax = fmaxf(tmax, v);
      }
    tmax = fmaxf(tmax, __shfl_xor(tmax, 16, 64));
    tmax = fmaxf(tmax, __shfl_xor(tmax, 32, 64));
    float mnew = fmaxf(mrun, tmax);
    float r = __expf(mrun - mnew);
    float psum = 0.0f;
    for (int i = 0; i < 16; ++i) {
      sv[i] = __expf(sv[i] - mnew);
      psum += sv[i];
    }
    psum += __shfl_xor(psum, 16, 64);
    psum += __shfl_xor(psum, 32, 64);
    lsum = lsum * r + psum;
    mrun = mnew;
    for (int i = 0; i < 8; ++i) ct[i] = ct[i] * r;

    // pack P to bf16 pairs, redistribute to PV B-operand layout via shuffles
    unsigned pk0[4], pk1[4];
    for (int s = 0; s < 4; ++s) {
      pk0[s] = (unsigned)f2bf(sv[s * 4 + 0]) | ((unsigned)f2bf(sv[s * 4 + 1]) << 16);
      pk1[s] = (unsigned)f2bf(sv[s * 4 + 2]) | ((unsigned)f2bf(sv[s * 4 + 3]) << 16);
    }
    const int src1 = qi + ((g & 1) << 5);
    const int src2 = src1 + 16;
    const bool hi = (g & 2) != 0;
    for (int p = 0; p < 2; ++p) {
      unsigned a0 = __shfl(pk0[2 * p], src1, 64), b0 = __shfl(pk0[2 * p + 1], src1, 64);
      unsigned a1 = __shfl(pk1[2 * p], src1, 64), b1 = __shfl(pk1[2 * p + 1], src1, 64);
      unsigned a2 = __shfl(pk0[2 * p], src2, 64), b2 = __shfl(pk0[2 * p + 1], src2, 64);
      unsigned a3 = __shfl(pk1[2 * p], src2, 64), b3 = __shfl(pk1[2 * p + 1], src2, 64);
      u4 bw;
      bw.x = hi ? b0 : a0; bw.y = hi ? b1 : a1; bw.z = hi ? b2 : a2; bw.w = hi ? b3 : a3;
      short8 pf = __builtin_bit_cast(short8, bw);
      for (int d = 0; d < 8; ++d) {
        int dr = d * 16 + qi;
        short8 a = *(const short8*)(vl + dr * 128 + (((p * 4 + g) ^ (dr & 7))) * 16);
        ct[d] = __builtin_amdgcn_mfma_f32_16x16x32_bf16(a, pf, ct[d], 0, 0, 0);
      }
    }
  }
  float inv = 1.0f / lsum;
  for (int d = 0; d < 8; ++d) {
    us4 o;
    o.x = f2bf(ct[d][0] * inv); o.y = f2bf(ct[d][1] * inv);
    o.z = f2bf(ct[d][2] * inv); o.w = f2bf(ct[d][3] * inv);
    *(us4*)(ctx + (size_t)qrow * 1024 + h * 128 + d * 16 + g * 4) = o;
  }
}

// ---------------- residual + LayerNorm ----------------
__global__ __launch_bounds__(256) void ln_kernel(const float* __restrict__ x,
                                                 const float* __restrict__ dec,
                                                 const float* __restrict__ gw,
                                                 const float* __restrict__ bw,
                                                 float* __restrict__ out) {
  __shared__ float rs[256], rs2[256];
  int row = blockIdx.x, tid = threadIdx.x;
  float c[4];
  float s = 0.0f, s2 = 0.0f;
  for (int i = 0; i < 4; ++i) {
    int col = tid + i * 256;
    float v = x[(size_t)row * 1024 + col] + dec[(size_t)row * 1024 + col];
    c[i] = v; s += v; s2 += v * v;
  }
  rs[tid] = s; rs2[tid] = s2;
  __syncthreads();
  for (int st = 128; st > 0; st >>= 1) {
    if (tid < st) { rs[tid] += rs[tid + st]; rs2[tid] += rs2[tid + st]; }
    __syncthreads();
  }
  float mu = rs[0] * (1.0f / 1024.0f);
  float var = rs2[0] * (1.0f / 1024.0f) - mu * mu;
  float inv = rsqrtf(var + 1e-5f);
  for (int i = 0; i < 4; ++i) {
    int col = tid + i * 256;
    out[(size_t)row * 1024 + col] = (c[i] - mu) * inv * gw[col] + bw[col];
  }
}

// ---------------- importance scorer (f32 exact) ----------------
__global__ __launch_bounds__(256) void imp_kernel(const float* __restrict__ x,
                                                  const float* __restrict__ w1,
                                                  const float* __restrict__ b1,
                                                  const float* __restrict__ w2,
                                                  const float* __restrict__ b2,
                                                  float* __restrict__ imp) {
  __shared__ float xs[1024];
  __shared__ float red[256];
  int row = blockIdx.x, tid = threadIdx.x;
  for (int i = 0; i < 4; ++i) xs[tid + i * 256] = x[(size_t)row * 1024 + tid + i * 256];
  __syncthreads();
  int col = tid & 63, kg = tid >> 6;
  float acc = 0.0f;
  for (int k = kg * 256; k < kg * 256 + 256; ++k) acc += xs[k] * w1[k * 64 + col];
  red[tid] = acc;
  __syncthreads();
  if (tid < 64) {
    float sv = red[tid] + red[tid + 64] + red[tid + 128] + red[tid + 192] + b1[tid];
    red[tid] = gelu_f(sv) * w2[tid];
  }
  __syncthreads();
  if (tid == 0) {
    float s = 0.0f;
    for (int i = 0; i < 64; ++i) s += red[i];
    s += b2[0];
    imp[row] = 1.0f / (1.0f + expf(-s));
  }
}

// ---------------- per-batch top-k via bitonic sort (val desc, idx asc) ----------------
__global__ __launch_bounds__(512) void topk_kernel(const float* __restrict__ imp,
                                                   int* __restrict__ tidx) {
  __shared__ float v[1024];
  __shared__ int ix[1024];
  int b = blockIdx.x, tid = threadIdx.x;
  for (int i = tid; i < 1024; i += 512) { v[i] = imp[b * 1024 + i]; ix[i] = i; }
  __syncthreads();
  for (int k = 2; k <= 1024; k <<= 1) {
    for (int j = k >> 1; j > 0; j >>= 1) {
      for (int t = tid; t < 1024; t += 512) {
        int p = t ^ j;
        if (p > t) {
          float va = v[t], vb = v[p];
          int ia = ix[t], ib = ix[p];
          bool ord = (va > vb) || (va == vb && ia < ib);  // a precedes b
          bool up = ((t & k) == 0);
          if (up ? !ord : ord) { v[t] = vb; v[p] = va; ix[t] = ib; ix[p] = ia; }
        }
      }
      __syncthreads();
    }
  }
  for (int t = tid; t < TOPK; t += 512) tidx[b * TOPK + t] = ix[t];
}

// ---------------- sequential-EMA memory update, parallel per memory row ----------------
__global__ __launch_bounds__(256) void update_kernel(const float* __restrict__ x,
                                                     const float* __restrict__ mem,
                                                     const int* __restrict__ midx,
                                                     const int* __restrict__ tidx,
                                                     float* __restrict__ outm) {
  __shared__ int mi[NUPD];
  int row = blockIdx.x, tid = threadIdx.x;
  for (int i = tid; i < NUPD; i += 256) mi[i] = midx[i];
  __syncthreads();
  float acc[4];
  for (int i = 0; i < 4; ++i) acc[i] = mem[(size_t)row * 1024 + tid + i * 256];
  for (int j = 0; j < NUPD; ++j) {
    if (mi[j] == row) {
      int b = j / TOPK;
      int tr = tidx[j];
      const float* xr = x + ((size_t)b * 1024 + tr) * 1024;
      for (int i = 0; i < 4; ++i) acc[i] = 0.99f * acc[i] + 0.01f * xr[tid + i * 256];
    }
  }
  for (int i = 0; i < 4; ++i) outm[(size_t)row * 1024 + tid + i * 256] = acc[i];
}

// ---------------- host ----------------
extern "C" void kernel_launch(void* const* d_in, const int* in_sizes, int n_in,
                              void* d_out, int out_size, void* d_ws, size_t ws_size,
                              hipStream_t stream) {
  const float* x = (const float*)d_in[0];
  const float* memory_bank = (const float*)d_in[1];
  const int* memory_indices = (const int*)d_in[2];
  const float* enc_w1 = (const float*)d_in[3];
  const float* enc_b1 = (const float*)d_in[4];
  const float* enc_w2 = (const float*)d_in[5];
  const float* enc_b2 = (const float*)d_in[6];
  const float* wq = (const float*)d_in[7];
  const float* bq = (const float*)d_in[8];
  const float* wk = (const float*)d_in[9];
  const float* bk = (const float*)d_in[10];
  const float* wv = (const float*)d_in[11];
  const float* bv = (const float*)d_in[12];
  const float* wo = (const float*)d_in[13];
  const float* bo = (const float*)d_in[14];
  const float* dec_w1 = (const float*)d_in[15];
  const float* dec_b1 = (const float*)d_in[16];
  const float* dec_w2 = (const float*)d_in[17];
  const float* dec_b2 = (const float*)d_in[18];
  const float* ln_g = (const float*)d_in[19];
  const float* ln_b = (const float*)d_in[20];
  const float* imp_w1 = (const float*)d_in[21];
  const float* imp_b1 = (const float*)d_in[22];
  const float* imp_w2 = (const float*)d_in[23];
  const float* imp_b2 = (const float*)d_in[24];

  char* ws = (char*)d_ws;
  u16* buf0 = (u16*)(ws);                      // x_bf -> enc -> mem_out
  u16* buf1 = (u16*)(ws + (8ull << 20));       // enc1 -> q -> dec1
  u16* buf2 = (u16*)(ws + (16ull << 20));      // mem_bf -> ctx
  u16* buf3 = (u16*)(ws + (24ull << 20));      // k
  u16* buf4 = (u16*)(ws + (32ull << 20));      // vT [1024][4096]
  float* decb = (float*)(ws + (40ull << 20));  // dec f32, 16MB
  u16* wtb = (u16*)(ws + (56ull << 20));       // 8 x 2MB transposed bf16 weights
  float* impb = (float*)(ws + (72ull << 20));
  int* tidx = (int*)(ws + (72ull << 20) + (1 << 16));

  const int NM = 1024 * 1024;  // elements per weight matrix
  u16* wt_e1 = wtb + 0 * NM;
  u16* wt_e2 = wtb + 1 * NM;
  u16* wt_q = wtb + 2 * NM;
  u16* wt_k = wtb + 3 * NM;
  u16* wt_v = wtb + 4 * NM;
  u16* wt_o = wtb + 5 * NM;
  u16* wt_d1 = wtb + 6 * NM;
  u16* wt_d2 = wtb + 7 * NM;

  // convert activations / memory bank to bf16
  conv_kernel<<<4096, 256, 0, stream>>>(x, buf0, ROWS * D_MODEL / 4);
  conv_kernel<<<4096, 256, 0, stream>>>(memory_bank, buf2, ROWS * D_MODEL / 4);

  // transpose weights to [N][K] bf16
  dim3 tg(32, 32);
  wtrans_kernel<<<tg, 256, 0, stream>>>(enc_w1, wt_e1, 1024, 1024);
  wtrans_kernel<<<tg, 256, 0, stream>>>(enc_w2, wt_e2, 1024, 1024);
  wtrans_kernel<<<tg, 256, 0, stream>>>(wq, wt_q, 1024, 1024);
  wtrans_kernel<<<tg, 256, 0, stream>>>(wk, wt_k, 1024, 1024);
  wtrans_kernel<<<tg, 256, 0, stream>>>(wv, wt_v, 1024, 1024);
  wtrans_kernel<<<tg, 256, 0, stream>>>(wo, wt_o, 1024, 1024);
  wtrans_kernel<<<tg, 256, 0, stream>>>(dec_w1, wt_d1, 1024, 1024);
  wtrans_kernel<<<tg, 256, 0, stream>>>(dec_w2, wt_d2, 1024, 1024);

  dim3 gg(8, 32);  // N/128, M/128
  // encoder
  gemm_bt<1><<<gg, 256, 0, stream>>>(buf0, wt_e1, enc_b1, buf1, ROWS, 1024, 1024);
  gemm_bt<0><<<gg, 256, 0, stream>>>(buf1, wt_e2, enc_b2, buf0, ROWS, 1024, 1024);
  // projections
  gemm_bt<0><<<gg, 256, 0, stream>>>(buf0, wt_q, bq, buf1, ROWS, 1024, 1024);
  gemm_bt<0><<<gg, 256, 0, stream>>>(buf2, wt_k, bk, buf3, ROWS, 1024, 1024);
  gemm_bt<3><<<gg, 256, 0, stream>>>(buf2, wt_v, bv, buf4, ROWS, 1024, 1024);
  // attention
  attn_kernel<<<dim3(16, NHEAD, NBATCH), 256, 0, stream>>>(buf1, buf3, buf4, buf2);
  // output projection + decoder
  gemm_bt<0><<<gg, 256, 0, stream>>>(buf2, wt_o, bo, buf0, ROWS, 1024, 1024);
  gemm_bt<1><<<gg, 256, 0, stream>>>(buf0, wt_d1, dec_b1, buf1, ROWS, 1024, 1024);
  gemm_bt<2><<<gg, 256, 0, stream>>>(buf1, wt_d2, dec_b2, decb, ROWS, 1024, 1024);
  // residual + LN -> out
  ln_kernel<<<4096, 256, 0, stream>>>(x, decb, ln_g, ln_b, (float*)d_out);
  // memory update path (f32 exact)
  imp_kernel<<<4096, 256, 0, stream>>>(x, imp_w1, imp_b1, imp_w2, imp_b2, impb);
  topk_kernel<<<NBATCH, 512, 0, stream>>>(impb, tidx);
  update_kernel<<<4096, 256, 0, stream>>>(x, memory_bank, memory_indices, tidx,
                                          (float*)d_out + ROWS * D_MODEL);
}

// Round 2
// 840.862 us; speedup vs baseline: 1.1400x; 1.1400x over previous
//
#include <hip/hip_runtime.h>

typedef unsigned short u16;
typedef __attribute__((ext_vector_type(4))) int i4;
typedef __attribute__((ext_vector_type(4))) unsigned u4;
typedef __attribute__((ext_vector_type(4))) unsigned short us4;
typedef __attribute__((ext_vector_type(8))) short short8;
typedef __attribute__((ext_vector_type(4))) float f4;

#define D_MODEL 1024
#define ROWS 4096      // B*L and MEM_SIZE
#define NHEAD 8
#define DH 128
#define TOPK 409
#define NUPD 1636      // B*TOPK
#define NBATCH 4
#define MAXC 64        // max chained updates tracked per memory row

__device__ __forceinline__ u16 f2bf(float f) {
  unsigned u = __builtin_bit_cast(unsigned, f);
  u += 0x7fffu + ((u >> 16) & 1u);
  return (u16)(u >> 16);
}
__device__ __forceinline__ float gelu_f(float v) {
  return 0.5f * v * (1.0f + erff(v * 0.70710678118654752f));
}
__device__ __forceinline__ void gload16(const void* g, void* l) {
  __builtin_amdgcn_global_load_lds((const __attribute__((address_space(1))) void*)g,
                                   (__attribute__((address_space(3))) void*)l, 16, 0, 0);
}

// ---------------- convert f32 -> bf16 (vectorized) ----------------
__global__ __launch_bounds__(256) void conv_kernel(const float* __restrict__ in,
                                                   u16* __restrict__ out, int n4) {
  int i = blockIdx.x * 256 + threadIdx.x;
  if (i < n4) {
    f4 v = ((const f4*)in)[i];
    us4 o;
    o.x = f2bf(v.x); o.y = f2bf(v.y); o.z = f2bf(v.z); o.w = f2bf(v.w);
    ((us4*)out)[i] = o;
  }
}

// ---------------- weight transpose: w[K][N] f32 -> wt[N][K] bf16 ----------------
__global__ __launch_bounds__(256) void wtrans_kernel(const float* __restrict__ w,
                                                     u16* __restrict__ wt, int K, int N) {
  __shared__ float t[32][33];
  int tx = threadIdx.x & 31, ty = threadIdx.x >> 5;
  int k0 = blockIdx.y * 32, n0 = blockIdx.x * 32;
  for (int r = 0; r < 4; ++r)
    t[ty + r * 8][tx] = w[(size_t)(k0 + ty + r * 8) * N + n0 + tx];
  __syncthreads();
  for (int r = 0; r < 4; ++r)
    wt[(size_t)(n0 + ty + r * 8) * K + k0 + tx] = f2bf(t[tx][ty + r * 8]);
}

// ---------------- bf16 GEMM: C[M][N] = A[M][K] * BT[N][K]^T + bias ----------------
// EPI: 0 = bf16 store, 1 = GELU + bf16 store, 2 = f32 store, 3 = bf16 transposed store (C^T [N][M])
template <int EPI>
__global__ __launch_bounds__(256) void gemm_bt(const u16* __restrict__ A,
                                               const u16* __restrict__ BT,
                                               const float* __restrict__ bias,
                                               void* __restrict__ C, int M, int N, int K) {
  __shared__ __align__(16) u16 al[128 * 32];
  __shared__ __align__(16) u16 bl[128 * 32];
  const int tid = threadIdx.x;
  const int lane = tid & 63, wid = tid >> 6;
  const int g = lane >> 4, qi = lane & 15;
  const int m0 = blockIdx.y * 128, n0 = blockIdx.x * 128;
  const int wr = wid >> 1, wc = wid & 1;
  f4 acc[4][4] = {};
  const int nk = K >> 5;
  const int c0 = tid, c1 = tid + 256;
  const int ar0 = c0 >> 2, ab0 = (c0 & 3) * 8;
  const int ar1 = c1 >> 2, ab1 = (c1 & 3) * 8;
  for (int kt = 0; kt < nk; ++kt) {
    const int k0 = kt * 32;
    gload16(A + (size_t)(m0 + ar0) * K + k0 + ab0, (char*)al + c0 * 16);
    gload16(A + (size_t)(m0 + ar1) * K + k0 + ab1, (char*)al + c1 * 16);
    gload16(BT + (size_t)(n0 + ar0) * K + k0 + ab0, (char*)bl + c0 * 16);
    gload16(BT + (size_t)(n0 + ar1) * K + k0 + ab1, (char*)bl + c1 * 16);
    __syncthreads();
    short8 af[4], bfr[4];
    for (int i = 0; i < 4; ++i)
      af[i] = *(const short8*)((const char*)al + (wr * 64 + i * 16 + qi) * 64 + g * 16);
    for (int sn = 0; sn < 4; ++sn)
      bfr[sn] = *(const short8*)((const char*)bl + (wc * 64 + sn * 16 + qi) * 64 + g * 16);
    for (int i = 0; i < 4; ++i)
      for (int sn = 0; sn < 4; ++sn)
        acc[i][sn] = __builtin_amdgcn_mfma_f32_16x16x32_bf16(af[i], bfr[sn], acc[i][sn], 0, 0, 0);
    __syncthreads();
  }
  if constexpr (EPI == 3) {
    // transposed store via padded LDS (conflict-free column read), coalesced global write
    __shared__ u16 t[4][64][66];
    for (int i = 0; i < 4; ++i)
      for (int sn = 0; sn < 4; ++sn) {
        float bv = bias[n0 + wc * 64 + sn * 16 + qi];
        for (int jj = 0; jj < 4; ++jj)
          t[wid][i * 16 + g * 4 + jj][sn * 16 + qi] = f2bf(acc[i][sn][jj] + bv);
      }
    __syncthreads();
    for (int nl = 0; nl < 64; ++nl) {
      u16 v = t[wid][lane][nl];
      ((u16*)C)[(size_t)(n0 + wc * 64 + nl) * M + m0 + wr * 64 + lane] = v;
    }
  } else {
    for (int i = 0; i < 4; ++i) {
      int row = m0 + wr * 64 + i * 16 + g * 4;
      for (int sn = 0; sn < 4; ++sn) {
        int col = n0 + wc * 64 + sn * 16 + qi;
        float bv = bias[col];
        for (int jj = 0; jj < 4; ++jj) {
          float v = acc[i][sn][jj] + bv;
          if constexpr (EPI == 1) v = gelu_f(v);
          if constexpr (EPI == 2)
            ((float*)C)[(size_t)(row + jj) * N + col] = v;
          else
            ((u16*)C)[(size_t)(row + jj) * N + col] = f2bf(v);
        }
      }
    }
  }
}

// ---------------- flash cross-attention ----------------
// q[4096][1024] bf16, k[4096][1024] bf16, vT[1024][4096] bf16 -> ctx[4096][1024] bf16
// grid (L/64, H, B), 256 threads (4 waves, 16 q-rows each). Swapped QK^T: lane-local softmax rows.
__global__ __launch_bounds__(256) void attn_kernel(const u16* __restrict__ q,
                                                   const u16* __restrict__ kp,
                                                   const u16* __restrict__ vT,
                                                   u16* __restrict__ ctx) {
  __shared__ __align__(16) char kl[64 * 256];   // K tile [64][128] bf16, 16B-block XOR swizzle
  __shared__ __align__(16) char vl[128 * 128];  // V^T tile [128][64] bf16, swizzled
  const int tid = threadIdx.x;
  const int lane = tid & 63, wid = tid >> 6;
  const int g = lane >> 4, qi = lane & 15;
  const int h = blockIdx.y, b = blockIdx.z;
  const int qrow = b * 1024 + blockIdx.x * 64 + wid * 16 + qi;
  const float scale = 0.08838834764831845f;  // 1/sqrt(128)

  short8 qf[4];
  for (int kk = 0; kk < 4; ++kk)
    qf[kk] = *(const short8*)(q + (size_t)qrow * 1024 + h * 128 + kk * 32 + g * 8);

  f4 ct[8] = {};
  float mrun = -1e30f, lsum = 0.0f;

  for (int mt = 0; mt < 64; ++mt) {
    const int m0 = mt * 64;
    __syncthreads();
    for (int i = 0; i < 4; ++i) {  // stage K: 64 rows x 16 16B-blocks
      int c = tid + i * 256, r = c >> 4, blk = c & 15;
      *(i4*)(kl + r * 256 + (blk ^ (r & 7)) * 16) =
          *(const i4*)(kp + (size_t)(m0 + r) * 1024 + h * 128 + blk * 8);
    }
    for (int i = 0; i < 4; ++i) {  // stage V^T: 128 rows x 8 16B-blocks
      int c = tid + i * 256, r = c >> 3, blk = c & 7;
      *(i4*)(vl + r * 128 + (blk ^ (r & 7)) * 16) =
          *(const i4*)(vT + (size_t)(h * 128 + r) * 4096 + m0 + blk * 8);
    }
    __syncthreads();

    // S^T = K_tile x Q^T : lane holds S^T[n = 16s + 4g + jj][q = qi]
    f4 st[4] = {};
    for (int s = 0; s < 4; ++s) {
      int n = s * 16 + qi;
      const char* krow = kl + n * 256;
      int sw = n & 7;
      for (int kk = 0; kk < 4; ++kk) {
        short8 a = *(const short8*)(krow + ((kk * 4 + g) ^ sw) * 16);
        st[s] = __builtin_amdgcn_mfma_f32_16x16x32_bf16(a, qf[kk], st[s], 0, 0, 0);
      }
    }
    // online softmax (row = qi, replicated across the 4 lane-groups)
    float sv[16];
    float tmax = -1e30f;
    for (int s = 0; s < 4; ++s)
      for (int jj = 0; jj < 4; ++jj) {
        float v = st[s][jj] * scale;
        sv[s * 4 + jj] = v;
        tmax = fmaxf(tmax, v);
      }
    tmax = fmaxf(tmax, __shfl_xor(tmax, 16, 64));
    tmax = fmaxf(tmax, __shfl_xor(tmax, 32, 64));
    float mnew = fmaxf(mrun, tmax);
    float r = __expf(mrun - mnew);
    float psum = 0.0f;
    for (int i = 0; i < 16; ++i) {
      sv[i] = __expf(sv[i] - mnew);
      psum += sv[i];
    }
    psum += __shfl_xor(psum, 16, 64);
    psum += __shfl_xor(psum, 32, 64);
    lsum = lsum * r + psum;
    mrun = mnew;
    for (int i = 0; i < 8; ++i) ct[i] = ct[i] * r;

    // pack P to bf16 pairs, redistribute to PV B-operand layout via shuffles
    unsigned pk0[4], pk1[4];
    for (int s = 0; s < 4; ++s) {
      pk0[s] = (unsigned)f2bf(sv[s * 4 + 0]) | ((unsigned)f2bf(sv[s * 4 + 1]) << 16);
      pk1[s] = (unsigned)f2bf(sv[s * 4 + 2]) | ((unsigned)f2bf(sv[s * 4 + 3]) << 16);
    }
    const int src1 = qi + ((g & 1) << 5);
    const int src2 = src1 + 16;
    const bool hi = (g & 2) != 0;
    for (int p = 0; p < 2; ++p) {
      unsigned a0 = __shfl(pk0[2 * p], src1, 64), b0 = __shfl(pk0[2 * p + 1], src1, 64);
      unsigned a1 = __shfl(pk1[2 * p], src1, 64), b1 = __shfl(pk1[2 * p + 1], src1, 64);
      unsigned a2 = __shfl(pk0[2 * p], src2, 64), b2 = __shfl(pk0[2 * p + 1], src2, 64);
      unsigned a3 = __shfl(pk1[2 * p], src2, 64), b3 = __shfl(pk1[2 * p + 1], src2, 64);
      u4 bw;
      bw.x = hi ? b0 : a0; bw.y = hi ? b1 : a1; bw.z = hi ? b2 : a2; bw.w = hi ? b3 : a3;
      short8 pf = __builtin_bit_cast(short8, bw);
      for (int d = 0; d < 8; ++d) {
        int dr = d * 16 + qi;
        short8 a = *(const short8*)(vl + dr * 128 + (((p * 4 + g) ^ (dr & 7))) * 16);
        ct[d] = __builtin_amdgcn_mfma_f32_16x16x32_bf16(a, pf, ct[d], 0, 0, 0);
      }
    }
  }
  float inv = 1.0f / lsum;
  for (int d = 0; d < 8; ++d) {
    us4 o;
    o.x = f2bf(ct[d][0] * inv); o.y = f2bf(ct[d][1] * inv);
    o.z = f2bf(ct[d][2] * inv); o.w = f2bf(ct[d][3] * inv);
    *(us4*)(ctx + (size_t)qrow * 1024 + h * 128 + d * 16 + g * 4) = o;
  }
}

// ---------------- residual + LayerNorm ----------------
__global__ __launch_bounds__(256) void ln_kernel(const float* __restrict__ x,
                                                 const float* __restrict__ dec,
                                                 const float* __restrict__ gw,
                                                 const float* __restrict__ bw,
                                                 float* __restrict__ out) {
  __shared__ float rs[256], rs2[256];
  int row = blockIdx.x, tid = threadIdx.x;
  float c[4];
  float s = 0.0f, s2 = 0.0f;
  for (int i = 0; i < 4; ++i) {
    int col = tid + i * 256;
    float v = x[(size_t)row * 1024 + col] + dec[(size_t)row * 1024 + col];
    c[i] = v; s += v; s2 += v * v;
  }
  rs[tid] = s; rs2[tid] = s2;
  __syncthreads();
  for (int st = 128; st > 0; st >>= 1) {
    if (tid < st) { rs[tid] += rs[tid + st]; rs2[tid] += rs2[tid + st]; }
    __syncthreads();
  }
  float mu = rs[0] * (1.0f / 1024.0f);
  float var = rs2[0] * (1.0f / 1024.0f) - mu * mu;
  float inv = rsqrtf(var + 1e-5f);
  for (int i = 0; i < 4; ++i) {
    int col = tid + i * 256;
    out[(size_t)row * 1024 + col] = (c[i] - mu) * inv * gw[col] + bw[col];
  }
}

// ---------------- importance scorer (f32 exact) ----------------
__global__ __launch_bounds__(256) void imp_kernel(const float* __restrict__ x,
                                                  const float* __restrict__ w1,
                                                  const float* __restrict__ b1,
                                                  const float* __restrict__ w2,
                                                  const float* __restrict__ b2,
                                                  float* __restrict__ imp) {
  __shared__ float xs[1024];
  __shared__ float red[256];
  int row = blockIdx.x, tid = threadIdx.x;
  for (int i = 0; i < 4; ++i) xs[tid + i * 256] = x[(size_t)row * 1024 + tid + i * 256];
  __syncthreads();
  int col = tid & 63, kg = tid >> 6;
  float acc = 0.0f;
  for (int k = kg * 256; k < kg * 256 + 256; ++k) acc += xs[k] * w1[k * 64 + col];
  red[tid] = acc;
  __syncthreads();
  if (tid < 64) {
    float sv = red[tid] + red[tid + 64] + red[tid + 128] + red[tid + 192] + b1[tid];
    red[tid] = gelu_f(sv) * w2[tid];
  }
  __syncthreads();
  if (tid == 0) {
    float s = 0.0f;
    for (int i = 0; i < 64; ++i) s += red[i];
    s += b2[0];
    imp[row] = 1.0f / (1.0f + expf(-s));
  }
}

// ---------------- per-batch top-k via bitonic sort (val desc, idx asc) ----------------
__global__ __launch_bounds__(512) void topk_kernel(const float* __restrict__ imp,
                                                   int* __restrict__ tidx) {
  __shared__ float v[1024];
  __shared__ int ix[1024];
  int b = blockIdx.x, tid = threadIdx.x;
  for (int i = tid; i < 1024; i += 512) { v[i] = imp[b * 1024 + i]; ix[i] = i; }
  __syncthreads();
  for (int k = 2; k <= 1024; k <<= 1) {
    for (int j = k >> 1; j > 0; j >>= 1) {
      for (int t = tid; t < 1024; t += 512) {
        int p = t ^ j;
        if (p > t) {
          float va = v[t], vb = v[p];
          int ia = ix[t], ib = ix[p];
          bool ord = (va > vb) || (va == vb && ia < ib);  // a precedes b
          bool up = ((t & k) == 0);
          if (up ? !ord : ord) { v[t] = vb; v[p] = va; ix[t] = ib; ix[p] = ia; }
        }
      }
      __syncthreads();
    }
  }
  for (int t = tid; t < TOPK; t += 512) tidx[b * TOPK + t] = ix[t];
}

// ---------------- EMA update, pass 1: per-row ordered update lists ----------------
// One block. For update j (in reference order), rank = #earlier updates to same row.
// slot[row*MAXC + rank] = j. cnt[row] = number of updates to row.
__global__ __launch_bounds__(1024) void rank_kernel(const int* __restrict__ midx,
                                                    int* __restrict__ cnt,
                                                    int* __restrict__ slot) {
  __shared__ int mi[NUPD];
  __shared__ int lcnt[ROWS];
  int tid = threadIdx.x;
  for (int i = tid; i < NUPD; i += 1024) mi[i] = midx[i];
  for (int i = tid; i < ROWS; i += 1024) lcnt[i] = 0;
  __syncthreads();
  for (int j = tid; j < NUPD; j += 1024) {
    int r = mi[j], rank = 0;
    for (int jp = 0; jp < j; ++jp) rank += (mi[jp] == r) ? 1 : 0;
    if (rank < MAXC) slot[r * MAXC + rank] = j;
    atomicAdd(&lcnt[r], 1);
  }
  __syncthreads();
  for (int i = tid; i < ROWS; i += 1024) cnt[i] = lcnt[i] < MAXC ? lcnt[i] : MAXC;
}

// ---------------- EMA update, pass 2: apply (one block per memory row) ----------------
__global__ __launch_bounds__(256) void apply_kernel(const float* __restrict__ x,
                                                    const float* __restrict__ mem,
                                                    const int* __restrict__ tidx,
                                                    const int* __restrict__ cnt,
                                                    const int* __restrict__ slot,
                                                    float* __restrict__ outm) {
  int row = blockIdx.x, tid = threadIdx.x;
  f4 acc = ((const f4*)(mem + (size_t)row * 1024))[tid];
  int c = cnt[row];
  for (int t = 0; t < c; ++t) {
    int j = slot[row * MAXC + t];
    int b = j / TOPK;
    int tr = tidx[j];
    f4 xv = ((const f4*)(x + ((size_t)b * 1024 + tr) * 1024))[tid];
    acc = acc * 0.99f + xv * 0.01f;
  }
  ((f4*)(outm + (size_t)row * 1024))[tid] = acc;
}

// ---------------- host ----------------
extern "C" void kernel_launch(void* const* d_in, const int* in_sizes, int n_in,
                              void* d_out, int out_size, void* d_ws, size_t ws_size,
                              hipStream_t stream) {
  const float* x = (const float*)d_in[0];
  const float* memory_bank = (const float*)d_in[1];
  const int* memory_indices = (const int*)d_in[2];
  const float* enc_w1 = (const float*)d_in[3];
  const float* enc_b1 = (const float*)d_in[4];
  const float* enc_w2 = (const float*)d_in[5];
  const float* enc_b2 = (const float*)d_in[6];
  const float* wq = (const float*)d_in[7];
  const float* bq = (const float*)d_in[8];
  const float* wk = (const float*)d_in[9];
  const float* bk = (const float*)d_in[10];
  const float* wv = (const float*)d_in[11];
  const float* bv = (const float*)d_in[12];
  const float* wo = (const float*)d_in[13];
  const float* bo = (const float*)d_in[14];
  const float* dec_w1 = (const float*)d_in[15];
  const float* dec_b1 = (const float*)d_in[16];
  const float* dec_w2 = (const float*)d_in[17];
  const float* dec_b2 = (const float*)d_in[18];
  const float* ln_g = (const float*)d_in[19];
  const float* ln_b = (const float*)d_in[20];
  const float* imp_w1 = (const float*)d_in[21];
  const float* imp_b1 = (const float*)d_in[22];
  const float* imp_w2 = (const float*)d_in[23];
  const float* imp_b2 = (const float*)d_in[24];

  char* ws = (char*)d_ws;
  u16* buf0 = (u16*)(ws);                      // x_bf -> enc -> mem_out
  u16* buf1 = (u16*)(ws + (8ull << 20));       // enc1 -> q -> dec1
  u16* buf2 = (u16*)(ws + (16ull << 20));      // mem_bf -> ctx
  u16* buf3 = (u16*)(ws + (24ull << 20));      // k
  u16* buf4 = (u16*)(ws + (32ull << 20));      // vT [1024][4096]
  float* decb = (float*)(ws + (40ull << 20));  // dec f32, 16MB (dead after ln -> reused by cnt/slot)
  u16* wtb = (u16*)(ws + (56ull << 20));       // 8 x 2MB transposed bf16 weights
  float* impb = (float*)(ws + (72ull << 20));
  int* tidx = (int*)(ws + (72ull << 20) + (1 << 16));
  // EMA scratch lives in the decb region, used only after ln_kernel has consumed decb
  int* cnt = (int*)(ws + (40ull << 20));
  int* slot = (int*)(ws + (40ull << 20) + (1 << 16));  // 4096*MAXC*4 = 1 MB

  const int NM = 1024 * 1024;  // elements per weight matrix
  u16* wt_e1 = wtb + 0 * NM;
  u16* wt_e2 = wtb + 1 * NM;
  u16* wt_q = wtb + 2 * NM;
  u16* wt_k = wtb + 3 * NM;
  u16* wt_v = wtb + 4 * NM;
  u16* wt_o = wtb + 5 * NM;
  u16* wt_d1 = wtb + 6 * NM;
  u16* wt_d2 = wtb + 7 * NM;

  // convert activations / memory bank to bf16
  conv_kernel<<<4096, 256, 0, stream>>>(x, buf0, ROWS * D_MODEL / 4);
  conv_kernel<<<4096, 256, 0, stream>>>(memory_bank, buf2, ROWS * D_MODEL / 4);

  // transpose weights to [N][K] bf16
  dim3 tg(32, 32);
  wtrans_kernel<<<tg, 256, 0, stream>>>(enc_w1, wt_e1, 1024, 1024);
  wtrans_kernel<<<tg, 256, 0, stream>>>(enc_w2, wt_e2, 1024, 1024);
  wtrans_kernel<<<tg, 256, 0, stream>>>(wq, wt_q, 1024, 1024);
  wtrans_kernel<<<tg, 256, 0, stream>>>(wk, wt_k, 1024, 1024);
  wtrans_kernel<<<tg, 256, 0, stream>>>(wv, wt_v, 1024, 1024);
  wtrans_kernel<<<tg, 256, 0, stream>>>(wo, wt_o, 1024, 1024);
  wtrans_kernel<<<tg, 256, 0, stream>>>(dec_w1, wt_d1, 1024, 1024);
  wtrans_kernel<<<tg, 256, 0, stream>>>(dec_w2, wt_d2, 1024, 1024);

  dim3 gg(8, 32);  // N/128, M/128
  // encoder
  gemm_bt<1><<<gg, 256, 0, stream>>>(buf0, wt_e1, enc_b1, buf1, ROWS, 1024, 1024);
  gemm_bt<0><<<gg, 256, 0, stream>>>(buf1, wt_e2, enc_b2, buf0, ROWS, 1024, 1024);
  // projections
  gemm_bt<0><<<gg, 256, 0, stream>>>(buf0, wt_q, bq, buf1, ROWS, 1024, 1024);
  gemm_bt<0><<<gg, 256, 0, stream>>>(buf2, wt_k, bk, buf3, ROWS, 1024, 1024);
  gemm_bt<3><<<gg, 256, 0, stream>>>(buf2, wt_v, bv, buf4, ROWS, 1024, 1024);
  // attention
  attn_kernel<<<dim3(16, NHEAD, NBATCH), 256, 0, stream>>>(buf1, buf3, buf4, buf2);
  // output projection + decoder
  gemm_bt<0><<<gg, 256, 0, stream>>>(buf2, wt_o, bo, buf0, ROWS, 1024, 1024);
  gemm_bt<1><<<gg, 256, 0, stream>>>(buf0, wt_d1, dec_b1, buf1, ROWS, 1024, 1024);
  gemm_bt<2><<<gg, 256, 0, stream>>>(buf1, wt_d2, dec_b2, decb, ROWS, 1024, 1024);
  // residual + LN -> out
  ln_kernel<<<4096, 256, 0, stream>>>(x, decb, ln_g, ln_b, (float*)d_out);
  // memory update path (f32 exact)
  imp_kernel<<<4096, 256, 0, stream>>>(x, imp_w1, imp_b1, imp_w2, imp_b2, impb);
  topk_kernel<<<NBATCH, 512, 0, stream>>>(impb, tidx);
  rank_kernel<<<1, 1024, 0, stream>>>(memory_indices, cnt, slot);
  apply_kernel<<<4096, 256, 0, stream>>>(x, memory_bank, tidx, cnt, slot,
                                         (float*)d_out + (size_t)ROWS * D_MODEL);
}

// Round 3
// 508.027 us; speedup vs baseline: 1.8869x; 1.6552x over previous
//
#include <hip/hip_runtime.h>

typedef unsigned short u16;
typedef __attribute__((ext_vector_type(4))) int i4;
typedef __attribute__((ext_vector_type(4))) unsigned u4;
typedef __attribute__((ext_vector_type(4))) unsigned short us4;
typedef __attribute__((ext_vector_type(8))) short short8;
typedef __attribute__((ext_vector_type(4))) float f4;

#define D_MODEL 1024
#define ROWS 4096      // B*L and MEM_SIZE
#define NHEAD 8
#define DH 128
#define TOPK 409
#define NUPD 1636      // B*TOPK
#define NBATCH 4
#define MAXC 64        // max chained updates tracked per memory row

__device__ __forceinline__ u16 f2bf(float f) {
  unsigned u = __builtin_bit_cast(unsigned, f);
  u += 0x7fffu + ((u >> 16) & 1u);
  return (u16)(u >> 16);
}
__device__ __forceinline__ float gelu_f(float v) {
  return 0.5f * v * (1.0f + erff(v * 0.70710678118654752f));
}
__device__ __forceinline__ void gload16(const void* g, void* l) {
  __builtin_amdgcn_global_load_lds((const __attribute__((address_space(1))) void*)g,
                                   (__attribute__((address_space(3))) void*)l, 16, 0, 0);
}

// ---------------- convert f32 -> bf16 (vectorized) ----------------
__global__ __launch_bounds__(256) void conv_kernel(const float* __restrict__ in,
                                                   u16* __restrict__ out, int n4) {
  int i = blockIdx.x * 256 + threadIdx.x;
  if (i < n4) {
    f4 v = ((const f4*)in)[i];
    us4 o;
    o.x = f2bf(v.x); o.y = f2bf(v.y); o.z = f2bf(v.z); o.w = f2bf(v.w);
    ((us4*)out)[i] = o;
  }
}

// ---------------- fused weight transpose: 8x w[1024][1024] f32 -> wt[N][K] bf16 ----------------
__global__ __launch_bounds__(256) void wtrans8_kernel(const float* s0, const float* s1,
                                                      const float* s2, const float* s3,
                                                      const float* s4, const float* s5,
                                                      const float* s6, const float* s7,
                                                      u16* __restrict__ dst) {
  const float* srcs[8] = {s0, s1, s2, s3, s4, s5, s6, s7};
  const float* w = srcs[blockIdx.z];
  u16* wt = dst + (size_t)blockIdx.z * (1024 * 1024);
  __shared__ float t[32][33];
  int tx = threadIdx.x & 31, ty = threadIdx.x >> 5;
  int k0 = blockIdx.y * 32, n0 = blockIdx.x * 32;
  for (int r = 0; r < 4; ++r)
    t[ty + r * 8][tx] = w[(size_t)(k0 + ty + r * 8) * 1024 + n0 + tx];
  __syncthreads();
  for (int r = 0; r < 4; ++r)
    wt[(size_t)(n0 + ty + r * 8) * 1024 + k0 + tx] = f2bf(t[tx][ty + r * 8]);
}

// ---------------- bf16 GEMM: C[M][N] = A[M][K] * BT[N][K]^T + bias ----------------
// BM=128 BN=64 BK=32, 4 waves, double-buffered LDS, 2-phase schedule, XOR-swizzled LDS.
// EPI: 0 = bf16 store, 1 = GELU + bf16 store, 2 = f32 store, 3 = bf16 transposed store (C^T [N][M])
template <int EPI>
__global__ __launch_bounds__(256) void gemm_bt(const u16* __restrict__ A,
                                               const u16* __restrict__ BT,
                                               const float* __restrict__ bias,
                                               void* __restrict__ C, int M, int N, int K) {
  // LDS slot (r, blk) holds global 16B-block (blk ^ ((r>>1)&3)) of row r -> 2-way reads
  __shared__ __align__(16) char al[2 * 128 * 64];  // 2 x [128 rows x 64B]
  __shared__ __align__(16) char bl[2 * 64 * 64];   // 2 x [64 rows x 64B]
  const int tid = threadIdx.x;
  const int lane = tid & 63, wid = tid >> 6;
  const int g = lane >> 4, qi = lane & 15;
  const int m0 = blockIdx.y * 128, n0 = blockIdx.x * 64;
  const int wr = wid >> 1, wc = wid & 1;
  f4 acc[4][2] = {};
  const int nk = K >> 5;

  // staging slot geometry (precomputed)
  const int a0r = tid >> 2, a0b = (tid & 3) ^ ((a0r >> 1) & 3);
  const int c1 = tid + 256;
  const int a1r = c1 >> 2, a1b = (c1 & 3) ^ ((a1r >> 1) & 3);
  const int b0r = tid >> 2, b0b = (tid & 3) ^ ((b0r >> 1) & 3);

#define STAGE(buf, kt)                                                                   \
  {                                                                                      \
    const int k0_ = (kt) * 32;                                                           \
    gload16(A + (size_t)(m0 + a0r) * K + k0_ + a0b * 8, al + (buf) * 8192 + tid * 16);   \
    gload16(A + (size_t)(m0 + a1r) * K + k0_ + a1b * 8, al + (buf) * 8192 + c1 * 16);    \
    gload16(BT + (size_t)(n0 + b0r) * K + k0_ + b0b * 8, bl + (buf) * 4096 + tid * 16);  \
  }

  STAGE(0, 0);
  __syncthreads();
  int cur = 0;
  for (int kt = 0; kt < nk; ++kt) {
    if (kt + 1 < nk) STAGE(cur ^ 1, kt + 1);
    short8 af[4], bfr[2];
    for (int i = 0; i < 4; ++i) {
      int r = wr * 64 + i * 16 + qi;
      af[i] = *(const short8*)(al + cur * 8192 + r * 64 + ((g ^ ((r >> 1) & 3))) * 16);
    }
    for (int sn = 0; sn < 2; ++sn) {
      int r = wc * 32 + sn * 16 + qi;
      bfr[sn] = *(const short8*)(bl + cur * 4096 + r * 64 + ((g ^ ((r >> 1) & 3))) * 16);
    }
    for (int i = 0; i < 4; ++i)
      for (int sn = 0; sn < 2; ++sn)
        acc[i][sn] = __builtin_amdgcn_mfma_f32_16x16x32_bf16(af[i], bfr[sn], acc[i][sn], 0, 0, 0);
    __syncthreads();
    cur ^= 1;
  }
#undef STAGE

  if constexpr (EPI == 3) {
    // transposed store: C^T[N][M]; stage through padded LDS for coalesced writes
    __shared__ u16 t[64][132];
    for (int i = 0; i < 4; ++i)
      for (int sn = 0; sn < 2; ++sn) {
        int nl = wc * 32 + sn * 16 + qi;
        float bv = bias[n0 + nl];
        for (int jj = 0; jj < 4; ++jj)
          t[nl][wr * 64 + i * 16 + g * 4 + jj] = f2bf(acc[i][sn][jj] + bv);
      }
    __syncthreads();
    int r = tid >> 2, cg = tid & 3;
    for (int v = 0; v < 4; ++v) {
      us4 val = *(const us4*)&t[r][cg * 32 + v * 8];
      *(us4*)&((u16*)C)[(size_t)(n0 + r) * M + m0 + cg * 32 + v * 8] = val;
    }
  } else {
    for (int i = 0; i < 4; ++i) {
      int row = m0 + wr * 64 + i * 16 + g * 4;
      for (int sn = 0; sn < 2; ++sn) {
        int col = n0 + wc * 32 + sn * 16 + qi;
        float bv = bias[col];
        for (int jj = 0; jj < 4; ++jj) {
          float v = acc[i][sn][jj] + bv;
          if constexpr (EPI == 1) v = gelu_f(v);
          if constexpr (EPI == 2)
            ((float*)C)[(size_t)(row + jj) * N + col] = v;
          else
            ((u16*)C)[(size_t)(row + jj) * N + col] = f2bf(v);
        }
      }
    }
  }
}

// ---------------- flash cross-attention ----------------
// q[4096][1024] bf16, k[4096][1024] bf16, vT[1024][4096] bf16 -> ctx[4096][1024] bf16
// grid (L/128, H, B), 512 threads (8 waves, 16 q-rows each). Swapped QK^T: lane-local softmax rows.
__global__ __launch_bounds__(512) void attn_kernel(const u16* __restrict__ q,
                                                   const u16* __restrict__ kp,
                                                   const u16* __restrict__ vT,
                                                   u16* __restrict__ ctx) {
  __shared__ __align__(16) char kl[64 * 256];   // K tile [64][128] bf16, 16B-block XOR swizzle
  __shared__ __align__(16) char vl[128 * 128];  // V^T tile [128][64] bf16, swizzled
  const int tid = threadIdx.x;
  const int lane = tid & 63, wid = tid >> 6;
  const int g = lane >> 4, qi = lane & 15;
  const int h = blockIdx.y, b = blockIdx.z;
  const int qrow = b * 1024 + blockIdx.x * 128 + wid * 16 + qi;
  const float scale = 0.08838834764831845f;  // 1/sqrt(128)

  short8 qf[4];
  for (int kk = 0; kk < 4; ++kk)
    qf[kk] = *(const short8*)(q + (size_t)qrow * 1024 + h * 128 + kk * 32 + g * 8);

  f4 ct[8] = {};
  float mrun = -1e30f, lsum = 0.0f;

  for (int mt = 0; mt < 64; ++mt) {
    const int m0 = mt * 64;
    __syncthreads();
    for (int i = 0; i < 2; ++i) {  // stage K: 64 rows x 16 16B-blocks
      int c = tid + i * 512, r = c >> 4, blk = c & 15;
      *(i4*)(kl + r * 256 + (blk ^ (r & 7)) * 16) =
          *(const i4*)(kp + (size_t)(m0 + r) * 1024 + h * 128 + blk * 8);
    }
    for (int i = 0; i < 2; ++i) {  // stage V^T: 128 rows x 8 16B-blocks
      int c = tid + i * 512, r = c >> 3, blk = c & 7;
      *(i4*)(vl + r * 128 + (blk ^ (r & 7)) * 16) =
          *(const i4*)(vT + (size_t)(h * 128 + r) * 4096 + m0 + blk * 8);
    }
    __syncthreads();

    // S^T = K_tile x Q^T : lane holds S^T[n][q = qi]
    f4 st[4] = {};
    for (int s = 0; s < 4; ++s) {
      int n = s * 16 + qi;
      const char* krow = kl + n * 256;
      int sw = n & 7;
      for (int kk = 0; kk < 4; ++kk) {
        short8 a = *(const short8*)(krow + ((kk * 4 + g) ^ sw) * 16);
        st[s] = __builtin_amdgcn_mfma_f32_16x16x32_bf16(a, qf[kk], st[s], 0, 0, 0);
      }
    }
    // online softmax (row = qi, distributed across the 4 lane-groups)
    float sv[16];
    float tmax = -1e30f;
    for (int s = 0; s < 4; ++s)
      for (int jj = 0; jj < 4; ++jj) {
        float v = st[s][jj] * scale;
        sv[s * 4 + jj] = v;
        tmax = fmaxf(tmax, v);
      }
    tmax = fmaxf(tmax, __shfl_xor(tmax, 16, 64));
    tmax = fmaxf(tmax, __shfl_xor(tmax, 32, 64));
    float mnew = fmaxf(mrun, tmax);
    float r = __expf(mrun - mnew);
    float psum = 0.0f;
    for (int i = 0; i < 16; ++i) {
      sv[i] = __expf(sv[i] - mnew);
      psum += sv[i];
    }
    psum += __shfl_xor(psum, 16, 64);
    psum += __shfl_xor(psum, 32, 64);
    lsum = lsum * r + psum;
    mrun = mnew;
    for (int i = 0; i < 8; ++i) ct[i] = ct[i] * r;

    // pack P to bf16 pairs, redistribute to PV B-operand layout via shuffles
    unsigned pk0[4], pk1[4];
    for (int s = 0; s < 4; ++s) {
      pk0[s] = (unsigned)f2bf(sv[s * 4 + 0]) | ((unsigned)f2bf(sv[s * 4 + 1]) << 16);
      pk1[s] = (unsigned)f2bf(sv[s * 4 + 2]) | ((unsigned)f2bf(sv[s * 4 + 3]) << 16);
    }
    const int src1 = qi + ((g & 1) << 5);
    const int src2 = src1 + 16;
    const bool hi = (g & 2) != 0;
    for (int p = 0; p < 2; ++p) {
      unsigned a0 = __shfl(pk0[2 * p], src1, 64), b0 = __shfl(pk0[2 * p + 1], src1, 64);
      unsigned a1 = __shfl(pk1[2 * p], src1, 64), b1 = __shfl(pk1[2 * p + 1], src1, 64);
      unsigned a2 = __shfl(pk0[2 * p], src2, 64), b2 = __shfl(pk0[2 * p + 1], src2, 64);
      unsigned a3 = __shfl(pk1[2 * p], src2, 64), b3 = __shfl(pk1[2 * p + 1], src2, 64);
      u4 bw;
      bw.x = hi ? b0 : a0; bw.y = hi ? b1 : a1; bw.z = hi ? b2 : a2; bw.w = hi ? b3 : a3;
      short8 pf = __builtin_bit_cast(short8, bw);
      for (int d = 0; d < 8; ++d) {
        int dr = d * 16 + qi;
        short8 a = *(const short8*)(vl + dr * 128 + (((p * 4 + g) ^ (dr & 7))) * 16);
        ct[d] = __builtin_amdgcn_mfma_f32_16x16x32_bf16(a, pf, ct[d], 0, 0, 0);
      }
    }
  }
  float inv = 1.0f / lsum;
  for (int d = 0; d < 8; ++d) {
    us4 o;
    o.x = f2bf(ct[d][0] * inv); o.y = f2bf(ct[d][1] * inv);
    o.z = f2bf(ct[d][2] * inv); o.w = f2bf(ct[d][3] * inv);
    *(us4*)(ctx + (size_t)qrow * 1024 + h * 128 + d * 16 + g * 4) = o;
  }
}

// ---------------- residual + LayerNorm ----------------
__global__ __launch_bounds__(256) void ln_kernel(const float* __restrict__ x,
                                                 const float* __restrict__ dec,
                                                 const float* __restrict__ gw,
                                                 const float* __restrict__ bw,
                                                 float* __restrict__ out) {
  __shared__ float rs[256], rs2[256];
  int row = blockIdx.x, tid = threadIdx.x;
  float c[4];
  float s = 0.0f, s2 = 0.0f;
  for (int i = 0; i < 4; ++i) {
    int col = tid + i * 256;
    float v = x[(size_t)row * 1024 + col] + dec[(size_t)row * 1024 + col];
    c[i] = v; s += v; s2 += v * v;
  }
  rs[tid] = s; rs2[tid] = s2;
  __syncthreads();
  for (int st = 128; st > 0; st >>= 1) {
    if (tid < st) { rs[tid] += rs[tid + st]; rs2[tid] += rs2[tid + st]; }
    __syncthreads();
  }
  float mu = rs[0] * (1.0f / 1024.0f);
  float var = rs2[0] * (1.0f / 1024.0f) - mu * mu;
  float inv = rsqrtf(var + 1e-5f);
  for (int i = 0; i < 4; ++i) {
    int col = tid + i * 256;
    out[(size_t)row * 1024 + col] = (c[i] - mu) * inv * gw[col] + bw[col];
  }
}

// ---------------- importance scorer (f32, 8 rows/block, wave-shuffle reduce) ----------------
__global__ __launch_bounds__(256) void imp_kernel(const float* __restrict__ x,
                                                  const float* __restrict__ w1,
                                                  const float* __restrict__ b1,
                                                  const float* __restrict__ w2,
                                                  const float* __restrict__ b2,
                                                  float* __restrict__ imp) {
  __shared__ float xs[8][1024];
  int tid = threadIdx.x;
  int lane = tid & 63, wid = tid >> 6;
  size_t base = (size_t)blockIdx.x * 8192;
  for (int i = 0; i < 32; ++i) ((float*)xs)[tid + i * 256] = x[base + tid + i * 256];
  __syncthreads();
  int r0 = wid * 2, r1 = wid * 2 + 1;
  float a0 = 0.0f, a1 = 0.0f;
  for (int k = 0; k < 1024; ++k) {
    float wv = w1[k * 64 + lane];
    a0 += xs[r0][k] * wv;
    a1 += xs[r1][k] * wv;
  }
  float h0 = gelu_f(a0 + b1[lane]) * w2[lane];
  float h1 = gelu_f(a1 + b1[lane]) * w2[lane];
  for (int d = 1; d < 64; d <<= 1) {
    h0 += __shfl_xor(h0, d, 64);
    h1 += __shfl_xor(h1, d, 64);
  }
  if (lane == 0) {
    imp[blockIdx.x * 8 + r0] = 1.0f / (1.0f + expf(-(h0 + b2[0])));
    imp[blockIdx.x * 8 + r1] = 1.0f / (1.0f + expf(-(h1 + b2[0])));
  }
}

// ---------------- per-batch top-k via bitonic sort (val desc, idx asc) ----------------
__global__ __launch_bounds__(512) void topk_kernel(const float* __restrict__ imp,
                                                   int* __restrict__ tidx) {
  __shared__ float v[1024];
  __shared__ int ix[1024];
  int b = blockIdx.x, tid = threadIdx.x;
  for (int i = tid; i < 1024; i += 512) { v[i] = imp[b * 1024 + i]; ix[i] = i; }
  __syncthreads();
  for (int k = 2; k <= 1024; k <<= 1) {
    for (int j = k >> 1; j > 0; j >>= 1) {
      for (int t = tid; t < 1024; t += 512) {
        int p = t ^ j;
        if (p > t) {
          float va = v[t], vb = v[p];
          int ia = ix[t], ib = ix[p];
          bool ord = (va > vb) || (va == vb && ia < ib);  // a precedes b
          bool up = ((t & k) == 0);
          if (up ? !ord : ord) { v[t] = vb; v[p] = va; ix[t] = ib; ix[p] = ia; }
        }
      }
      __syncthreads();
    }
  }
  for (int t = tid; t < TOPK; t += 512) tidx[b * TOPK + t] = ix[t];
}

// ---------------- EMA update, pass 1: per-row ordered update lists ----------------
__global__ __launch_bounds__(1024) void rank_kernel(const int* __restrict__ midx,
                                                    int* __restrict__ cnt,
                                                    int* __restrict__ slot) {
  __shared__ int mi[NUPD];
  __shared__ int lcnt[ROWS];
  int tid = threadIdx.x;
  for (int i = tid; i < NUPD; i += 1024) mi[i] = midx[i];
  for (int i = tid; i < ROWS; i += 1024) lcnt[i] = 0;
  __syncthreads();
  for (int j = tid; j < NUPD; j += 1024) {
    int r = mi[j], rank = 0;
    for (int jp = 0; jp < j; ++jp) rank += (mi[jp] == r) ? 1 : 0;
    if (rank < MAXC) slot[r * MAXC + rank] = j;
    atomicAdd(&lcnt[r], 1);
  }
  __syncthreads();
  for (int i = tid; i < ROWS; i += 1024) cnt[i] = lcnt[i] < MAXC ? lcnt[i] : MAXC;
}

// ---------------- EMA update, pass 2: apply (one block per memory row) ----------------
__global__ __launch_bounds__(256) void apply_kernel(const float* __restrict__ x,
                                                    const float* __restrict__ mem,
                                                    const int* __restrict__ tidx,
                                                    const int* __restrict__ cnt,
                                                    const int* __restrict__ slot,
                                                    float* __restrict__ outm) {
  int row = blockIdx.x, tid = threadIdx.x;
  f4 acc = ((const f4*)(mem + (size_t)row * 1024))[tid];
  int c = cnt[row];
  for (int t = 0; t < c; ++t) {
    int j = slot[row * MAXC + t];
    int b = j / TOPK;
    int tr = tidx[j];
    f4 xv = ((const f4*)(x + ((size_t)b * 1024 + tr) * 1024))[tid];
    acc = acc * 0.99f + xv * 0.01f;
  }
  ((f4*)(outm + (size_t)row * 1024))[tid] = acc;
}

// ---------------- host ----------------
extern "C" void kernel_launch(void* const* d_in, const int* in_sizes, int n_in,
                              void* d_out, int out_size, void* d_ws, size_t ws_size,
                              hipStream_t stream) {
  const float* x = (const float*)d_in[0];
  const float* memory_bank = (const float*)d_in[1];
  const int* memory_indices = (const int*)d_in[2];
  const float* enc_w1 = (const float*)d_in[3];
  const float* enc_b1 = (const float*)d_in[4];
  const float* enc_w2 = (const float*)d_in[5];
  const float* enc_b2 = (const float*)d_in[6];
  const float* wq = (const float*)d_in[7];
  const float* bq = (const float*)d_in[8];
  const float* wk = (const float*)d_in[9];
  const float* bk = (const float*)d_in[10];
  const float* wv = (const float*)d_in[11];
  const float* bv = (const float*)d_in[12];
  const float* wo = (const float*)d_in[13];
  const float* bo = (const float*)d_in[14];
  const float* dec_w1 = (const float*)d_in[15];
  const float* dec_b1 = (const float*)d_in[16];
  const float* dec_w2 = (const float*)d_in[17];
  const float* dec_b2 = (const float*)d_in[18];
  const float* ln_g = (const float*)d_in[19];
  const float* ln_b = (const float*)d_in[20];
  const float* imp_w1 = (const float*)d_in[21];
  const float* imp_b1 = (const float*)d_in[22];
  const float* imp_w2 = (const float*)d_in[23];
  const float* imp_b2 = (const float*)d_in[24];

  char* ws = (char*)d_ws;
  u16* buf0 = (u16*)(ws);                      // x_bf -> enc -> mem_out
  u16* buf1 = (u16*)(ws + (8ull << 20));       // enc1 -> q -> dec1
  u16* buf2 = (u16*)(ws + (16ull << 20));      // mem_bf -> ctx
  u16* buf3 = (u16*)(ws + (24ull << 20));      // k
  u16* buf4 = (u16*)(ws + (32ull << 20));      // vT [1024][4096]
  float* decb = (float*)(ws + (40ull << 20));  // dec f32, 16MB (dead after ln -> reused by cnt/slot)
  u16* wtb = (u16*)(ws + (56ull << 20));       // 8 x 2MB transposed bf16 weights
  float* impb = (float*)(ws + (72ull << 20));
  int* tidx = (int*)(ws + (72ull << 20) + (1 << 16));
  // EMA scratch lives in the decb region, used only after ln_kernel has consumed decb
  int* cnt = (int*)(ws + (40ull << 20));
  int* slot = (int*)(ws + (40ull << 20) + (1 << 16));  // 4096*MAXC*4 = 1 MB

  const int NM = 1024 * 1024;  // elements per weight matrix
  u16* wt_e1 = wtb + 0 * NM;
  u16* wt_e2 = wtb + 1 * NM;
  u16* wt_q = wtb + 2 * NM;
  u16* wt_k = wtb + 3 * NM;
  u16* wt_v = wtb + 4 * NM;
  u16* wt_o = wtb + 5 * NM;
  u16* wt_d1 = wtb + 6 * NM;
  u16* wt_d2 = wtb + 7 * NM;

  // convert activations / memory bank to bf16
  conv_kernel<<<4096, 256, 0, stream>>>(x, buf0, ROWS * D_MODEL / 4);
  conv_kernel<<<4096, 256, 0, stream>>>(memory_bank, buf2, ROWS * D_MODEL / 4);

  // transpose all 8 weights to [N][K] bf16 in one dispatch
  wtrans8_kernel<<<dim3(32, 32, 8), 256, 0, stream>>>(enc_w1, enc_w2, wq, wk, wv, wo,
                                                      dec_w1, dec_w2, wtb);

  dim3 gg(16, 32);  // N/64, M/128 -> 512 blocks (2/CU)
  // encoder
  gemm_bt<1><<<gg, 256, 0, stream>>>(buf0, wt_e1, enc_b1, buf1, ROWS, 1024, 1024);
  gemm_bt<0><<<gg, 256, 0, stream>>>(buf1, wt_e2, enc_b2, buf0, ROWS, 1024, 1024);
  // projections
  gemm_bt<0><<<gg, 256, 0, stream>>>(buf0, wt_q, bq, buf1, ROWS, 1024, 1024);
  gemm_bt<0><<<gg, 256, 0, stream>>>(buf2, wt_k, bk, buf3, ROWS, 1024, 1024);
  gemm_bt<3><<<gg, 256, 0, stream>>>(buf2, wt_v, bv, buf4, ROWS, 1024, 1024);
  // attention
  attn_kernel<<<dim3(8, NHEAD, NBATCH), 512, 0, stream>>>(buf1, buf3, buf4, buf2);
  // output projection + decoder
  gemm_bt<0><<<gg, 256, 0, stream>>>(buf2, wt_o, bo, buf0, ROWS, 1024, 1024);
  gemm_bt<1><<<gg, 256, 0, stream>>>(buf0, wt_d1, dec_b1, buf1, ROWS, 1024, 1024);
  gemm_bt<2><<<gg, 256, 0, stream>>>(buf1, wt_d2, dec_b2, decb, ROWS, 1024, 1024);
  // residual + LN -> out
  ln_kernel<<<4096, 256, 0, stream>>>(x, decb, ln_g, ln_b, (float*)d_out);
  // memory update path (f32 exact)
  imp_kernel<<<512, 256, 0, stream>>>(x, imp_w1, imp_b1, imp_w2, imp_b2, impb);
  topk_kernel<<<NBATCH, 512, 0, stream>>>(impb, tidx);
  rank_kernel<<<1, 1024, 0, stream>>>(memory_indices, cnt, slot);
  apply_kernel<<<4096, 256, 0, stream>>>(x, memory_bank, tidx, cnt, slot,
                                         (float*)d_out + (size_t)ROWS * D_MODEL);
}

// Round 4
// 425.718 us; speedup vs baseline: 2.2517x; 1.1933x over previous
//
#include <hip/hip_runtime.h>

typedef unsigned short u16;
typedef __attribute__((ext_vector_type(4))) int i4;
typedef __attribute__((ext_vector_type(4))) unsigned u4;
typedef __attribute__((ext_vector_type(4))) unsigned short us4;
typedef __attribute__((ext_vector_type(8))) short short8;
typedef __attribute__((ext_vector_type(4))) float f4;

#define D_MODEL 1024
#define ROWS 4096      // B*L and MEM_SIZE
#define NHEAD 8
#define DH 128
#define TOPK 409
#define NUPD 1636      // B*TOPK
#define NBATCH 4
#define MAXC 64        // max chained updates tracked per memory row
#define NPART 2        // attention split-K parts
#define MRANGE 2048    // memory rows per part
#define ATTNROWS 32768 // B*H*L rows of (head-sliced) attention output

__device__ __forceinline__ u16 f2bf(float f) {
  unsigned u = __builtin_bit_cast(unsigned, f);
  u += 0x7fffu + ((u >> 16) & 1u);
  return (u16)(u >> 16);
}
__device__ __forceinline__ float bf2f(u16 b) {
  unsigned u = ((unsigned)b) << 16;
  return __builtin_bit_cast(float, u);
}
__device__ __forceinline__ float gelu_f(float v) {
  return 0.5f * v * (1.0f + erff(v * 0.70710678118654752f));
}
__device__ __forceinline__ void gload16(const void* g, void* l) {
  __builtin_amdgcn_global_load_lds((const __attribute__((address_space(1))) void*)g,
                                   (__attribute__((address_space(3))) void*)l, 16, 0, 0);
}

// ---------------- convert f32 -> bf16 (vectorized) ----------------
__global__ __launch_bounds__(256) void conv_kernel(const float* __restrict__ in,
                                                   u16* __restrict__ out, int n4) {
  int i = blockIdx.x * 256 + threadIdx.x;
  if (i < n4) {
    f4 v = ((const f4*)in)[i];
    us4 o;
    o.x = f2bf(v.x); o.y = f2bf(v.y); o.z = f2bf(v.z); o.w = f2bf(v.w);
    ((us4*)out)[i] = o;
  }
}

// ---------------- fused weight transpose: 8x w[1024][1024] f32 -> wt[N][K] bf16 ----------------
__global__ __launch_bounds__(256) void wtrans8_kernel(const float* s0, const float* s1,
                                                      const float* s2, const float* s3,
                                                      const float* s4, const float* s5,
                                                      const float* s6, const float* s7,
                                                      u16* __restrict__ dst) {
  const float* srcs[8] = {s0, s1, s2, s3, s4, s5, s6, s7};
  const float* w = srcs[blockIdx.z];
  u16* wt = dst + (size_t)blockIdx.z * (1024 * 1024);
  __shared__ float t[32][33];
  int tx = threadIdx.x & 31, ty = threadIdx.x >> 5;
  int k0 = blockIdx.y * 32, n0 = blockIdx.x * 32;
  for (int r = 0; r < 4; ++r)
    t[ty + r * 8][tx] = w[(size_t)(k0 + ty + r * 8) * 1024 + n0 + tx];
  __syncthreads();
  for (int r = 0; r < 4; ++r)
    wt[(size_t)(n0 + ty + r * 8) * 1024 + k0 + tx] = f2bf(t[tx][ty + r * 8]);
}

// ---------------- bf16 GEMM: C[M][N] = A[M][K] * BT[N][K]^T + bias ----------------
// BM=128 BN=64 BK=32, 4 waves, double-buffered LDS, 2-phase schedule, XOR-swizzled LDS.
// EPI: 0 = bf16 store, 1 = GELU + bf16 store, 2 = f32 store
template <int EPI>
__global__ __launch_bounds__(256) void gemm_bt(const u16* __restrict__ A,
                                               const u16* __restrict__ BT,
                                               const float* __restrict__ bias,
                                               void* __restrict__ C, int M, int N, int K) {
  __shared__ __align__(16) char al[2 * 128 * 64];  // 2 x [128 rows x 64B]
  __shared__ __align__(16) char bl[2 * 64 * 64];   // 2 x [64 rows x 64B]
  const int tid = threadIdx.x;
  const int lane = tid & 63, wid = tid >> 6;
  const int g = lane >> 4, qi = lane & 15;
  const int m0 = blockIdx.y * 128, n0 = blockIdx.x * 64;
  const int wr = wid >> 1, wc = wid & 1;
  f4 acc[4][2] = {};
  const int nk = K >> 5;

  const int a0r = tid >> 2, a0b = (tid & 3) ^ ((a0r >> 1) & 3);
  const int c1 = tid + 256;
  const int a1r = c1 >> 2, a1b = (c1 & 3) ^ ((a1r >> 1) & 3);
  const int b0r = tid >> 2, b0b = (tid & 3) ^ ((b0r >> 1) & 3);

#define STAGE(buf, kt)                                                                   \
  {                                                                                      \
    const int k0_ = (kt) * 32;                                                           \
    gload16(A + (size_t)(m0 + a0r) * K + k0_ + a0b * 8, al + (buf) * 8192 + tid * 16);   \
    gload16(A + (size_t)(m0 + a1r) * K + k0_ + a1b * 8, al + (buf) * 8192 + c1 * 16);    \
    gload16(BT + (size_t)(n0 + b0r) * K + k0_ + b0b * 8, bl + (buf) * 4096 + tid * 16);  \
  }

  STAGE(0, 0);
  __syncthreads();
  int cur = 0;
  for (int kt = 0; kt < nk; ++kt) {
    if (kt + 1 < nk) STAGE(cur ^ 1, kt + 1);
    short8 af[4], bfr[2];
    for (int i = 0; i < 4; ++i) {
      int r = wr * 64 + i * 16 + qi;
      af[i] = *(const short8*)(al + cur * 8192 + r * 64 + ((g ^ ((r >> 1) & 3))) * 16);
    }
    for (int sn = 0; sn < 2; ++sn) {
      int r = wc * 32 + sn * 16 + qi;
      bfr[sn] = *(const short8*)(bl + cur * 4096 + r * 64 + ((g ^ ((r >> 1) & 3))) * 16);
    }
    for (int i = 0; i < 4; ++i)
      for (int sn = 0; sn < 2; ++sn)
        acc[i][sn] = __builtin_amdgcn_mfma_f32_16x16x32_bf16(af[i], bfr[sn], acc[i][sn], 0, 0, 0);
    __syncthreads();
    cur ^= 1;
  }
#undef STAGE

  for (int i = 0; i < 4; ++i) {
    int row = m0 + wr * 64 + i * 16 + g * 4;
    for (int sn = 0; sn < 2; ++sn) {
      int col = n0 + wc * 32 + sn * 16 + qi;
      float bv = bias[col];
      for (int jj = 0; jj < 4; ++jj) {
        float v = acc[i][sn][jj] + bv;
        if constexpr (EPI == 1) v = gelu_f(v);
        if constexpr (EPI == 2)
          ((float*)C)[(size_t)(row + jj) * N + col] = v;
        else
          ((u16*)C)[(size_t)(row + jj) * N + col] = f2bf(v);
      }
    }
  }
}

// ---------------- merged K/V projection GEMM ----------------
// A = mem_bf [4096][1024]; BT = [wk^T ; wv^T] (2048 rows x 1024). Cols 0..1023 -> K (normal
// bf16 store), cols 1024..2047 -> V stored transposed as vT[1024][4096].
__global__ __launch_bounds__(256) void gemm_kv(const u16* __restrict__ A,
                                               const u16* __restrict__ BT,
                                               const float* __restrict__ bk,
                                               const float* __restrict__ bv,
                                               u16* __restrict__ Ck, u16* __restrict__ CvT) {
  __shared__ __align__(16) char pool[2 * 128 * 64 + 2 * 64 * 64];  // al | bl, reused as t
  char* al = pool;
  char* bl = pool + 2 * 128 * 64;
  const int tid = threadIdx.x;
  const int lane = tid & 63, wid = tid >> 6;
  const int g = lane >> 4, qi = lane & 15;
  const int m0 = blockIdx.y * 128, n0 = blockIdx.x * 64;
  const int wr = wid >> 1, wc = wid & 1;
  const int K = 1024, M = 4096;
  f4 acc[4][2] = {};

  const int a0r = tid >> 2, a0b = (tid & 3) ^ ((a0r >> 1) & 3);
  const int c1 = tid + 256;
  const int a1r = c1 >> 2, a1b = (c1 & 3) ^ ((a1r >> 1) & 3);
  const int b0r = tid >> 2, b0b = (tid & 3) ^ ((b0r >> 1) & 3);

#define STAGE(buf, kt)                                                                   \
  {                                                                                      \
    const int k0_ = (kt) * 32;                                                           \
    gload16(A + (size_t)(m0 + a0r) * K + k0_ + a0b * 8, al + (buf) * 8192 + tid * 16);   \
    gload16(A + (size_t)(m0 + a1r) * K + k0_ + a1b * 8, al + (buf) * 8192 + c1 * 16);    \
    gload16(BT + (size_t)(n0 + b0r) * K + k0_ + b0b * 8, bl + (buf) * 4096 + tid * 16);  \
  }

  STAGE(0, 0);
  __syncthreads();
  int cur = 0;
  for (int kt = 0; kt < 32; ++kt) {
    if (kt + 1 < 32) STAGE(cur ^ 1, kt + 1);
    short8 af[4], bfr[2];
    for (int i = 0; i < 4; ++i) {
      int r = wr * 64 + i * 16 + qi;
      af[i] = *(const short8*)(al + cur * 8192 + r * 64 + ((g ^ ((r >> 1) & 3))) * 16);
    }
    for (int sn = 0; sn < 2; ++sn) {
      int r = wc * 32 + sn * 16 + qi;
      bfr[sn] = *(const short8*)(bl + cur * 4096 + r * 64 + ((g ^ ((r >> 1) & 3))) * 16);
    }
    for (int i = 0; i < 4; ++i)
      for (int sn = 0; sn < 2; ++sn)
        acc[i][sn] = __builtin_amdgcn_mfma_f32_16x16x32_bf16(af[i], bfr[sn], acc[i][sn], 0, 0, 0);
    __syncthreads();
    cur ^= 1;
  }
#undef STAGE

  if (n0 < 1024) {  // K path: normal store
    for (int i = 0; i < 4; ++i) {
      int row = m0 + wr * 64 + i * 16 + g * 4;
      for (int sn = 0; sn < 2; ++sn) {
        int col = n0 + wc * 32 + sn * 16 + qi;
        float bvv = bk[col];
        for (int jj = 0; jj < 4; ++jj)
          Ck[(size_t)(row + jj) * 1024 + col] = f2bf(acc[i][sn][jj] + bvv);
      }
    }
  } else {  // V path: transposed store via padded LDS
    u16(*t)[132] = (u16(*)[132])pool;
    __syncthreads();
    for (int i = 0; i < 4; ++i)
      for (int sn = 0; sn < 2; ++sn) {
        int nl = wc * 32 + sn * 16 + qi;
        float bvv = bv[n0 - 1024 + nl];
        for (int jj = 0; jj < 4; ++jj)
          t[nl][wr * 64 + i * 16 + g * 4 + jj] = f2bf(acc[i][sn][jj] + bvv);
      }
    __syncthreads();
    int r = tid >> 2, cg = tid & 3;
    for (int v = 0; v < 4; ++v) {
      us4 val = *(const us4*)&t[r][cg * 32 + v * 8];
      *(us4*)&CvT[(size_t)(n0 - 1024 + r) * M + m0 + cg * 32 + v * 8] = val;
    }
  }
}

// ---------------- flash cross-attention, split-K over memory ----------------
// Flat grid 512: h = id%8 (XCD-pinned), part, qblk, b decoded from id/8.
// Writes unnormalized partial ct (bf16) + (m,l) per row; combine_kernel merges.
__global__ __launch_bounds__(512) void attn_kernel(const u16* __restrict__ q,
                                                   const u16* __restrict__ kp,
                                                   const u16* __restrict__ vT,
                                                   u16* __restrict__ ctp,
                                                   float* __restrict__ ml) {
  __shared__ __align__(16) char kl[64 * 256];   // K tile [64][128] bf16, 16B-block XOR swizzle
  __shared__ __align__(16) char vl[128 * 128];  // V^T tile [128][64] bf16, swizzled
  const int id = blockIdx.x;
  const int h = id & 7;
  const int rest = id >> 3;
  const int part = rest & 1;
  const int qblk = (rest >> 1) & 7;
  const int b = rest >> 4;
  const int tid = threadIdx.x;
  const int lane = tid & 63, wid = tid >> 6;
  const int g = lane >> 4, qi = lane & 15;
  const int qrow = b * 1024 + qblk * 128 + wid * 16 + qi;
  const float scale = 0.08838834764831845f;  // 1/sqrt(128)

  short8 qf[4];
  for (int kk = 0; kk < 4; ++kk)
    qf[kk] = *(const short8*)(q + (size_t)qrow * 1024 + h * 128 + kk * 32 + g * 8);

  // staging geometry (2 K-blocks + 2 V-blocks per thread)
  const int kc0 = tid, kc1 = tid + 512;
  const int kr0 = kc0 >> 4, kb0 = kc0 & 15, kr1 = kc1 >> 4, kb1 = kc1 & 15;
  const int vr0 = kc0 >> 3, vb0 = kc0 & 7, vr1 = kc1 >> 3, vb1 = kc1 & 7;
  const int kd0 = kr0 * 256 + (kb0 ^ (kr0 & 7)) * 16;
  const int kd1 = kr1 * 256 + (kb1 ^ (kr1 & 7)) * 16;
  const int vd0 = vr0 * 128 + (vb0 ^ (vr0 & 7)) * 16;
  const int vd1 = vr1 * 128 + (vb1 ^ (vr1 & 7)) * 16;
  const u16* kg0 = kp + (size_t)kr0 * 1024 + h * 128 + kb0 * 8;
  const u16* kg1 = kp + (size_t)kr1 * 1024 + h * 128 + kb1 * 8;
  const u16* vg0 = vT + (size_t)(h * 128 + vr0) * 4096 + vb0 * 8;
  const u16* vg1 = vT + (size_t)(h * 128 + vr1) * 4096 + vb1 * 8;

  i4 kreg0, kreg1, vreg0, vreg1;
  const int mbase = part * MRANGE;
#define LOADREGS(mt_)                                  \
  {                                                    \
    const int m0_ = mbase + (mt_) * 64;                \
    kreg0 = *(const i4*)(kg0 + (size_t)m0_ * 1024);    \
    kreg1 = *(const i4*)(kg1 + (size_t)m0_ * 1024);    \
    vreg0 = *(const i4*)(vg0 + m0_);                   \
    vreg1 = *(const i4*)(vg1 + m0_);                   \
  }

  f4 ct[8] = {};
  float mrun = -1e30f, lsum = 0.0f;

  LOADREGS(0);
  const int nt = MRANGE / 64;
  for (int mt = 0; mt < nt; ++mt) {
    __syncthreads();  // previous tile's consumers done
    *(i4*)(kl + kd0) = kreg0;
    *(i4*)(kl + kd1) = kreg1;
    *(i4*)(vl + vd0) = vreg0;
    *(i4*)(vl + vd1) = vreg1;
    __syncthreads();
    if (mt + 1 < nt) LOADREGS(mt + 1);  // in flight during compute

    // S^T = K_tile x Q^T : lane holds S^T[n][q = qi]
    f4 st[4] = {};
    for (int s = 0; s < 4; ++s) {
      int n = s * 16 + qi;
      const char* krow = kl + n * 256;
      int sw = n & 7;
      for (int kk = 0; kk < 4; ++kk) {
        short8 a = *(const short8*)(krow + ((kk * 4 + g) ^ sw) * 16);
        st[s] = __builtin_amdgcn_mfma_f32_16x16x32_bf16(a, qf[kk], st[s], 0, 0, 0);
      }
    }
    // online softmax (row = qi, distributed across the 4 lane-groups)
    float sv[16];
    float tmax = -1e30f;
    for (int s = 0; s < 4; ++s)
      for (int jj = 0; jj < 4; ++jj) {
        float v = st[s][jj] * scale;
        sv[s * 4 + jj] = v;
        tmax = fmaxf(tmax, v);
      }
    tmax = fmaxf(tmax, __shfl_xor(tmax, 16, 64));
    tmax = fmaxf(tmax, __shfl_xor(tmax, 32, 64));
    float mnew = fmaxf(mrun, tmax);
    float r = __expf(mrun - mnew);
    float psum = 0.0f;
    for (int i = 0; i < 16; ++i) {
      sv[i] = __expf(sv[i] - mnew);
      psum += sv[i];
    }
    psum += __shfl_xor(psum, 16, 64);
    psum += __shfl_xor(psum, 32, 64);
    lsum = lsum * r + psum;
    mrun = mnew;
    for (int i = 0; i < 8; ++i) ct[i] = ct[i] * r;

    // pack P to bf16 pairs, redistribute to PV B-operand layout via shuffles
    unsigned pk0[4], pk1[4];
    for (int s = 0; s < 4; ++s) {
      pk0[s] = (unsigned)f2bf(sv[s * 4 + 0]) | ((unsigned)f2bf(sv[s * 4 + 1]) << 16);
      pk1[s] = (unsigned)f2bf(sv[s * 4 + 2]) | ((unsigned)f2bf(sv[s * 4 + 3]) << 16);
    }
    const int src1 = qi + ((g & 1) << 5);
    const int src2 = src1 + 16;
    const bool hi = (g & 2) != 0;
    for (int p = 0; p < 2; ++p) {
      unsigned a0 = __shfl(pk0[2 * p], src1, 64), b0 = __shfl(pk0[2 * p + 1], src1, 64);
      unsigned a1 = __shfl(pk1[2 * p], src1, 64), b1 = __shfl(pk1[2 * p + 1], src1, 64);
      unsigned a2 = __shfl(pk0[2 * p], src2, 64), b2 = __shfl(pk0[2 * p + 1], src2, 64);
      unsigned a3 = __shfl(pk1[2 * p], src2, 64), b3 = __shfl(pk1[2 * p + 1], src2, 64);
      u4 bw;
      bw.x = hi ? b0 : a0; bw.y = hi ? b1 : a1; bw.z = hi ? b2 : a2; bw.w = hi ? b3 : a3;
      short8 pf = __builtin_bit_cast(short8, bw);
      for (int d = 0; d < 8; ++d) {
        int dr = d * 16 + qi;
        short8 a = *(const short8*)(vl + dr * 128 + (((p * 4 + g) ^ (dr & 7))) * 16);
        ct[d] = __builtin_amdgcn_mfma_f32_16x16x32_bf16(a, pf, ct[d], 0, 0, 0);
      }
    }
  }
#undef LOADREGS

  // write unnormalized partials
  const int orow = ((b * 8 + h) << 10) + qblk * 128 + wid * 16 + qi;
  if (g == 0) {
    ml[(size_t)(part * ATTNROWS + orow) * 2 + 0] = mrun;
    ml[(size_t)(part * ATTNROWS + orow) * 2 + 1] = lsum;
  }
  for (int d = 0; d < 8; ++d) {
    us4 o;
    o.x = f2bf(ct[d][0]); o.y = f2bf(ct[d][1]);
    o.z = f2bf(ct[d][2]); o.w = f2bf(ct[d][3]);
    *(us4*)(ctp + ((size_t)(part * ATTNROWS + orow)) * 128 + d * 16 + g * 4) = o;
  }
}

// ---------------- combine split-K partials -> ctx [4096][1024] bf16 ----------------
__global__ __launch_bounds__(256) void combine_kernel(const u16* __restrict__ ctp,
                                                      const float* __restrict__ ml,
                                                      u16* __restrict__ ctx) {
  int tid = threadIdx.x;
  int row = blockIdx.x * 16 + (tid >> 4);
  int dp = (tid & 15) * 8;
  float m0 = ml[(size_t)row * 2], l0 = ml[(size_t)row * 2 + 1];
  float m1 = ml[(size_t)(ATTNROWS + row) * 2], l1 = ml[(size_t)(ATTNROWS + row) * 2 + 1];
  float m = fmaxf(m0, m1);
  float s0 = __expf(m0 - m), s1 = __expf(m1 - m);
  float inv = 1.0f / (l0 * s0 + l1 * s1);
  short8 c0 = *(const short8*)(ctp + (size_t)row * 128 + dp);
  short8 c1 = *(const short8*)(ctp + (size_t)(ATTNROWS + row) * 128 + dp);
  us4 o[2];
  for (int i = 0; i < 8; ++i) {
    float f = (bf2f((u16)c0[i]) * s0 + bf2f((u16)c1[i]) * s1) * inv;
    ((u16*)o)[i] = f2bf(f);
  }
  int bb = row >> 13, hh = (row >> 10) & 7, qr = row & 1023;
  *(short8*)(ctx + (size_t)((bb << 10) + qr) * 1024 + hh * 128 + dp) =
      __builtin_bit_cast(short8, o);
}

// ---------------- residual + LayerNorm (also zeroes EMA cnt) ----------------
__global__ __launch_bounds__(256) void ln_kernel(const float* __restrict__ x,
                                                 const float* __restrict__ dec,
                                                 const float* __restrict__ gw,
                                                 const float* __restrict__ bw,
                                                 float* __restrict__ out,
                                                 int* __restrict__ cnt) {
  __shared__ float rs[256], rs2[256];
  int row = blockIdx.x, tid = threadIdx.x;
  if (tid == 0) cnt[row] = 0;
  float c[4];
  float s = 0.0f, s2 = 0.0f;
  for (int i = 0; i < 4; ++i) {
    int col = tid + i * 256;
    float v = x[(size_t)row * 1024 + col] + dec[(size_t)row * 1024 + col];
    c[i] = v; s += v; s2 += v * v;
  }
  rs[tid] = s; rs2[tid] = s2;
  __syncthreads();
  for (int st = 128; st > 0; st >>= 1) {
    if (tid < st) { rs[tid] += rs[tid + st]; rs2[tid] += rs2[tid + st]; }
    __syncthreads();
  }
  float mu = rs[0] * (1.0f / 1024.0f);
  float var = rs2[0] * (1.0f / 1024.0f) - mu * mu;
  float inv = rsqrtf(var + 1e-5f);
  for (int i = 0; i < 4; ++i) {
    int col = tid + i * 256;
    out[(size_t)row * 1024 + col] = (c[i] - mu) * inv * gw[col] + bw[col];
  }
}

// ---------------- importance scorer (f32, 8 rows/block, wave-shuffle reduce) ----------------
__global__ __launch_bounds__(256) void imp_kernel(const float* __restrict__ x,
                                                  const float* __restrict__ w1,
                                                  const float* __restrict__ b1,
                                                  const float* __restrict__ w2,
                                                  const float* __restrict__ b2,
                                                  float* __restrict__ imp) {
  __shared__ float xs[8][1024];
  int tid = threadIdx.x;
  int lane = tid & 63, wid = tid >> 6;
  size_t base = (size_t)blockIdx.x * 8192;
  for (int i = 0; i < 32; ++i) ((float*)xs)[tid + i * 256] = x[base + tid + i * 256];
  __syncthreads();
  int r0 = wid * 2, r1 = wid * 2 + 1;
  float a0 = 0.0f, a1 = 0.0f;
  for (int k = 0; k < 1024; ++k) {
    float wv = w1[k * 64 + lane];
    a0 += xs[r0][k] * wv;
    a1 += xs[r1][k] * wv;
  }
  float h0 = gelu_f(a0 + b1[lane]) * w2[lane];
  float h1 = gelu_f(a1 + b1[lane]) * w2[lane];
  for (int d = 1; d < 64; d <<= 1) {
    h0 += __shfl_xor(h0, d, 64);
    h1 += __shfl_xor(h1, d, 64);
  }
  if (lane == 0) {
    imp[blockIdx.x * 8 + r0] = 1.0f / (1.0f + expf(-(h0 + b2[0])));
    imp[blockIdx.x * 8 + r1] = 1.0f / (1.0f + expf(-(h1 + b2[0])));
  }
}

// ---------------- per-batch top-k via bitonic sort (val desc, idx asc) ----------------
__global__ __launch_bounds__(512) void topk_kernel(const float* __restrict__ imp,
                                                   int* __restrict__ tidx) {
  __shared__ float v[1024];
  __shared__ int ix[1024];
  int b = blockIdx.x, tid = threadIdx.x;
  for (int i = tid; i < 1024; i += 512) { v[i] = imp[b * 1024 + i]; ix[i] = i; }
  __syncthreads();
  for (int k = 2; k <= 1024; k <<= 1) {
    for (int j = k >> 1; j > 0; j >>= 1) {
      for (int t = tid; t < 1024; t += 512) {
        int p = t ^ j;
        if (p > t) {
          float va = v[t], vb = v[p];
          int ia = ix[t], ib = ix[p];
          bool ord = (va > vb) || (va == vb && ia < ib);  // a precedes b
          bool up = ((t & k) == 0);
          if (up ? !ord : ord) { v[t] = vb; v[p] = va; ix[t] = ib; ix[p] = ia; }
        }
      }
      __syncthreads();
    }
  }
  for (int t = tid; t < TOPK; t += 512) tidx[b * TOPK + t] = ix[t];
}

// ---------------- EMA update, pass 1: per-row ordered update lists ----------------
// 13 blocks x 128 threads; thread j computes rank among earlier updates to same row.
// cnt must be pre-zeroed (done in ln_kernel).
__global__ __launch_bounds__(128) void rank_kernel(const int* __restrict__ midx,
                                                   int* __restrict__ cnt,
                                                   int* __restrict__ slot) {
  __shared__ int mi[NUPD];
  int tid = threadIdx.x;
  for (int i = tid; i < NUPD; i += 128) mi[i] = midx[i];
  __syncthreads();
  int j = blockIdx.x * 128 + tid;
  if (j < NUPD) {
    int r = mi[j], rank = 0;
    for (int jp = 0; jp < j; ++jp) rank += (mi[jp] == r) ? 1 : 0;
    if (rank < MAXC) slot[r * MAXC + rank] = j;
    atomicAdd(&cnt[r], 1);
  }
}

// ---------------- EMA update, pass 2: apply (one block per memory row) ----------------
__global__ __launch_bounds__(256) void apply_kernel(const float* __restrict__ x,
                                                    const float* __restrict__ mem,
                                                    const int* __restrict__ tidx,
                                                    const int* __restrict__ cnt,
                                                    const int* __restrict__ slot,
                                                    float* __restrict__ outm) {
  int row = blockIdx.x, tid = threadIdx.x;
  f4 acc = ((const f4*)(mem + (size_t)row * 1024))[tid];
  int c = cnt[row];
  c = c < MAXC ? c : MAXC;
  for (int t = 0; t < c; ++t) {
    int j = slot[row * MAXC + t];
    int b = j / TOPK;
    int tr = tidx[j];
    f4 xv = ((const f4*)(x + ((size_t)b * 1024 + tr) * 1024))[tid];
    acc = acc * 0.99f + xv * 0.01f;
  }
  ((f4*)(outm + (size_t)row * 1024))[tid] = acc;
}

// ---------------- host ----------------
extern "C" void kernel_launch(void* const* d_in, const int* in_sizes, int n_in,
                              void* d_out, int out_size, void* d_ws, size_t ws_size,
                              hipStream_t stream) {
  const float* x = (const float*)d_in[0];
  const float* memory_bank = (const float*)d_in[1];
  const int* memory_indices = (const int*)d_in[2];
  const float* enc_w1 = (const float*)d_in[3];
  const float* enc_b1 = (const float*)d_in[4];
  const float* enc_w2 = (const float*)d_in[5];
  const float* enc_b2 = (const float*)d_in[6];
  const float* wq = (const float*)d_in[7];
  const float* bq = (const float*)d_in[8];
  const float* wk = (const float*)d_in[9];
  const float* bk = (const float*)d_in[10];
  const float* wv = (const float*)d_in[11];
  const float* bv = (const float*)d_in[12];
  const float* wo = (const float*)d_in[13];
  const float* bo = (const float*)d_in[14];
  const float* dec_w1 = (const float*)d_in[15];
  const float* dec_b1 = (const float*)d_in[16];
  const float* dec_w2 = (const float*)d_in[17];
  const float* dec_b2 = (const float*)d_in[18];
  const float* ln_g = (const float*)d_in[19];
  const float* ln_b = (const float*)d_in[20];
  const float* imp_w1 = (const float*)d_in[21];
  const float* imp_b1 = (const float*)d_in[22];
  const float* imp_w2 = (const float*)d_in[23];
  const float* imp_b2 = (const float*)d_in[24];

  char* ws = (char*)d_ws;
  u16* buf0 = (u16*)(ws);                      // x_bf -> enc -> ml -> mem_out
  u16* buf1 = (u16*)(ws + (8ull << 20));       // enc1 -> q -> dec1
  u16* buf2 = (u16*)(ws + (16ull << 20));      // mem_bf -> ctx
  u16* buf3 = (u16*)(ws + (24ull << 20));      // k -> cnt/slot
  u16* buf4 = (u16*)(ws + (32ull << 20));      // vT [1024][4096]
  float* decb = (float*)(ws + (40ull << 20));  // attn partials ctp -> dec f32 (16MB)
  u16* wtb = (u16*)(ws + (56ull << 20));       // 8 x 2MB transposed bf16 weights
  float* impb = (float*)(ws + (72ull << 20));
  int* tidx = (int*)(ws + (72ull << 20) + (1 << 16));
  // attention split-K partials (regions dead at attn time)
  u16* ctp = (u16*)decb;          // 2*32768*128*2B = 16 MB
  float* ml = (float*)buf0;       // 2*32768*2*4B = 512 KB (enc dead after q GEMM)
  // EMA scratch in buf3 region (k dead after attn)
  int* cnt = (int*)buf3;
  int* slot = (int*)(ws + (24ull << 20) + (1 << 16));

  const int NM = 1024 * 1024;  // elements per weight matrix
  u16* wt_e1 = wtb + 0 * NM;
  u16* wt_e2 = wtb + 1 * NM;
  u16* wt_q = wtb + 2 * NM;
  u16* wt_k = wtb + 3 * NM;  // wk^T ; wv^T contiguous for merged KV GEMM
  u16* wt_o = wtb + 5 * NM;
  u16* wt_d1 = wtb + 6 * NM;
  u16* wt_d2 = wtb + 7 * NM;

  // convert activations / memory bank to bf16
  conv_kernel<<<4096, 256, 0, stream>>>(x, buf0, ROWS * D_MODEL / 4);
  conv_kernel<<<4096, 256, 0, stream>>>(memory_bank, buf2, ROWS * D_MODEL / 4);

  // transpose all 8 weights to [N][K] bf16 in one dispatch
  wtrans8_kernel<<<dim3(32, 32, 8), 256, 0, stream>>>(enc_w1, enc_w2, wq, wk, wv, wo,
                                                      dec_w1, dec_w2, wtb);

  dim3 gg(16, 32);  // N/64, M/128 -> 512 blocks (2/CU)
  // encoder
  gemm_bt<1><<<gg, 256, 0, stream>>>(buf0, wt_e1, enc_b1, buf1, ROWS, 1024, 1024);
  gemm_bt<0><<<gg, 256, 0, stream>>>(buf1, wt_e2, enc_b2, buf0, ROWS, 1024, 1024);
  // q projection
  gemm_bt<0><<<gg, 256, 0, stream>>>(buf0, wt_q, bq, buf1, ROWS, 1024, 1024);
  // merged k/v projection (1024 blocks, 4/CU)
  gemm_kv<<<dim3(32, 32), 256, 0, stream>>>(buf2, wt_k, bk, bv, buf3, buf4);
  // attention: split-K(2), XCD-pinned heads
  attn_kernel<<<512, 512, 0, stream>>>(buf1, buf3, buf4, ctp, ml);
  combine_kernel<<<2048, 256, 0, stream>>>(ctp, ml, buf2);
  // output projection + decoder
  gemm_bt<0><<<gg, 256, 0, stream>>>(buf2, wt_o, bo, buf0, ROWS, 1024, 1024);
  gemm_bt<1><<<gg, 256, 0, stream>>>(buf0, wt_d1, dec_b1, buf1, ROWS, 1024, 1024);
  gemm_bt<2><<<gg, 256, 0, stream>>>(buf1, wt_d2, dec_b2, decb, ROWS, 1024, 1024);
  // residual + LN -> out (also zeroes cnt)
  ln_kernel<<<4096, 256, 0, stream>>>(x, decb, ln_g, ln_b, (float*)d_out, cnt);
  // memory update path (f32 exact)
  imp_kernel<<<512, 256, 0, stream>>>(x, imp_w1, imp_b1, imp_w2, imp_b2, impb);
  topk_kernel<<<NBATCH, 512, 0, stream>>>(impb, tidx);
  rank_kernel<<<13, 128, 0, stream>>>(memory_indices, cnt, slot);
  apply_kernel<<<4096, 256, 0, stream>>>(x, memory_bank, tidx, cnt, slot,
                                         (float*)d_out + (size_t)ROWS * D_MODEL);
}